// Round 9
// baseline (984.120 us; speedup 1.0000x reference)
//
#include <hip/hip_runtime.h>

#define N_TOT 8192
#define BHALF 4096
#define D_DIM 512
#define BM 256            // block tile 256x256
#define NTILE 32          // N_TOT / BM
#define NBLOCKS 528       // NTILE*(NTILE+1)/2 upper-triangle tiles
#define TBK 64            // K per chunk (double-buffered)
#define NK 8              // D_DIM / TBK
#define PANEL (BM * TBK)  // 16384 bf16 elems = 32 KB per buffer

// Z is scaled by sqrt(2/ln2) at normalize time, so acc = (2/ln2)*cos and
// exp(2*cos) == exp2(acc) -> bare v_exp_f32 in the epilogue.
// The positive LOGIT (2*cos) is recovered as acc * ln2.
#define ZSCALE 1.69864368f      // sqrt(2/ln(2))
#define LN2F   0.69314718f

typedef float f32x4 __attribute__((ext_vector_type(4)));
typedef short s16x8 __attribute__((ext_vector_type(8)));  // 8 bf16 in 4 VGPRs

__device__ __forceinline__ unsigned short f2bf(float x) {
    union { float f; unsigned int u; } v; v.f = x;
    unsigned int lsb = (v.u >> 16) & 1u;
    unsigned int r = v.u + 0x7fffu + lsb;   // round-to-nearest-even
    return (unsigned short)(r >> 16);
}

__device__ __forceinline__ float fast_exp2(float x) {
#if __has_builtin(__builtin_amdgcn_exp2f)
    return __builtin_amdgcn_exp2f(x);
#else
    return exp2f(x);
#endif
}

// Kernel 1: row L2-normalize [zjs; zis] * ZSCALE -> bf16 Z.
// Blocks 0..31 zero rowsum.
__global__ __launch_bounds__(256) void normalize_kernel(
    const float* __restrict__ zis, const float* __restrict__ zjs,
    unsigned short* __restrict__ zb, float* __restrict__ rowsum)
{
    if (blockIdx.x < 32) rowsum[blockIdx.x * 256 + threadIdx.x] = 0.0f;
    int wave = threadIdx.x >> 6;
    int lane = threadIdx.x & 63;
    int row  = blockIdx.x * 4 + wave;
    const float* src = (row < BHALF) ? (zjs + (size_t)row * D_DIM)
                                     : (zis + (size_t)(row - BHALF) * D_DIM);
    const float4* src4 = (const float4*)src;
    float4 v0 = src4[lane * 2];
    float4 v1 = src4[lane * 2 + 1];
    float ss = v0.x*v0.x + v0.y*v0.y + v0.z*v0.z + v0.w*v0.w
             + v1.x*v1.x + v1.y*v1.y + v1.z*v1.z + v1.w*v1.w;
    #pragma unroll
    for (int off = 1; off < 64; off <<= 1) ss += __shfl_xor(ss, off);
    float scale = ZSCALE / fmaxf(sqrtf(ss), 1e-8f);

    float vals[8] = {v0.x, v0.y, v0.z, v0.w, v1.x, v1.y, v1.z, v1.w};
    unsigned short u[8];
    #pragma unroll
    for (int i = 0; i < 8; ++i) u[i] = f2bf(vals[i] * scale);
    uint4 o;
    o.x = u[0] | ((unsigned)u[1] << 16);
    o.y = u[2] | ((unsigned)u[3] << 16);
    o.z = u[4] | ((unsigned)u[5] << 16);
    o.w = u[6] | ((unsigned)u[7] << 16);
    ((uint4*)(zb + (size_t)row * D_DIM))[lane] = o;
}

// Kernel 2: upper-triangle 256x256 tiles of exp2(Zs.Zs^T), diag masked.
//
// ROUND 9 — 256^2 / 8-wave geometry (m201 regime) with the R6-PROVEN
// 2-phase counted-vmcnt loop. R8 proved direct-global gather fails
// (compiler won't pipeline, VGPR 76, 2.5x slower); R6's limit was LDS-pipe
// bytes (~60% busy). Wave tile 128x64 cuts LDS fragment-read bytes/FLOP by
// 25% vs 64x64 (24KB reads per 64-MFMA chunk vs 8KB per 16-MFMA chunk).
// acc[8][4] = 128 VGPR; __launch_bounds__(512,2) caps VGPR at 256.
// LDS: 2 x 32KB x {A,B} = 128KB -> 1 block/CU, 2 waves/SIMD.
//
// XCD-CHUNKED SWIZZLE (verified R6: FETCH 72.8->19.9 MB): 528 = 8*66,
// bijective; per-XCD concurrent panel set ~3 MB fits the 4 MB L2.
//
// LDS swizzle (128B rows, 8 x 16B units): unit for (row r, k-unit c8) is
// r*8 + (c8 ^ (r&7)). Fragment reads spread 16 lanes across all 8 slots
// (2-way alias = free, m136; 0 bank conflicts measured on the same scheme
// R0-R7). Staging dest linear in tid (global_load_lds requirement); the
// global SOURCE address is pre-swizzled: c8 = (tid&7) ^ ((tid>>3)&7),
// invariant across rounds since rnd*64 = 0 (mod 8).
__global__ __launch_bounds__(512, 2) void ntxent_tri_kernel(
    const unsigned short* __restrict__ zb, float* __restrict__ rowsum,
    float* __restrict__ pos_ws)
{
    __shared__ unsigned short As[2 * PANEL];   // 64 KB (2 buffers)
    __shared__ unsigned short Bs[2 * PANEL];   // 64 KB
    // rsum/csum (512 floats) overlay onto As buf0 after the K-loop.

    const int tid  = threadIdx.x;
    const int wave = tid >> 6;
    const int lane = tid & 63;
    const int cq   = lane & 15;
    const int quad = lane >> 4;
    const int wr   = wave >> 2;    // wave row 0..1 (128 rows each)
    const int wc   = wave & 3;     // wave col 0..3 (64 cols each)

    // XCD-chunked bijective remap (528 = 8 * 66).
    const int swzbid = (blockIdx.x & 7) * (NBLOCKS / 8) + (blockIdx.x >> 3);

    // swzbid -> (I,J), J-group-major (8 J-panels/group), I-major in group.
    int g = 0, rem = swzbid;
    while (rem >= 64 * g + 36) { rem -= 64 * g + 36; ++g; }
    int I, J;
    if (rem < 64 * g) { I = rem >> 3; J = 8 * g + (rem & 7); }
    else {
        rem -= 64 * g;
        int ii = 0;
        while (rem >= 8 - ii) { rem -= 8 - ii; ++ii; }
        I = 8 * g + ii;
        J = I + rem;
    }
    const int rowbase = I * BM;
    const int colbase = J * BM;
    const bool diagblk = (I == J);
    const bool posblk  = (J == I + NTILE / 2);   // contains (i, i+BHALF) pairs

    // Staging: round rnd covers rows rnd*64 + (tid>>3); unit slot tid&7;
    // pre-swizzled global k-unit c8 = (tid&7) ^ ((tid>>3)&7).
    const int c8s = (tid & 7) ^ ((tid >> 3) & 7);
    const unsigned short* gA[4];
    const unsigned short* gB[4];
    #pragma unroll
    for (int rnd = 0; rnd < 4; ++rnd) {
        int r = rnd * 64 + (tid >> 3);
        gA[rnd] = zb + (size_t)(rowbase + r) * D_DIM + c8s * 8;
        gB[rnd] = zb + (size_t)(colbase + r) * D_DIM + c8s * 8;
    }

    // Fragment-read constants: row ra = wr*128 + t*16 + cq (A, t=0..7),
    // rb = wc*64 + t*16 + cq (B, t=0..3); ra&7 == rb&7 == cq&7.
    const int swzq = cq & 7;
    int aOff[8], bOff[4];
    #pragma unroll
    for (int t = 0; t < 8; ++t) aOff[t] = (wr * 128 + t * 16 + cq) * TBK;
    #pragma unroll
    for (int t = 0; t < 4; ++t) bOff[t] = (wc * 64 + t * 16 + cq) * TBK;

    f32x4 acc[8][4];
    #pragma unroll
    for (int a = 0; a < 8; ++a)
        #pragma unroll
        for (int b = 0; b < 4; ++b)
            acc[a][b] = (f32x4){0.f, 0.f, 0.f, 0.f};

#define STAGE(buf) do {                                                          \
    const int dbase = (buf) * PANEL;                                             \
    _Pragma("unroll")                                                            \
    for (int rnd = 0; rnd < 4; ++rnd) {                                          \
        __builtin_amdgcn_global_load_lds(                                        \
            (const __attribute__((address_space(1))) unsigned int*)gA[rnd],      \
            (__attribute__((address_space(3))) unsigned int*)                    \
                &As[dbase + rnd * 4096 + tid * 8], 16, 0, 0);                    \
        __builtin_amdgcn_global_load_lds(                                        \
            (const __attribute__((address_space(1))) unsigned int*)gB[rnd],      \
            (__attribute__((address_space(3))) unsigned int*)                    \
                &Bs[dbase + rnd * 4096 + tid * 8], 16, 0, 0);                    \
        gA[rnd] += TBK; gB[rnd] += TBK;                                          \
    }                                                                            \
} while (0)

#define COMPUTE(buf) do {                                                        \
    const int cbase = (buf) * PANEL;                                             \
    _Pragma("unroll")                                                            \
    for (int kk = 0; kk < 2; ++kk) {                                             \
        s16x8 bfr[4];                                                            \
        const int c8 = (kk << 2) | quad;                                         \
        _Pragma("unroll")                                                        \
        for (int t = 0; t < 4; ++t)                                              \
            bfr[t] = *(const s16x8*)&Bs[cbase + bOff[t] + ((c8 ^ swzq) << 3)];   \
        _Pragma("unroll")                                                        \
        for (int t = 0; t < 8; ++t) {                                            \
            s16x8 afr = *(const s16x8*)&As[cbase + aOff[t] + ((c8 ^ swzq) << 3)];\
            _Pragma("unroll")                                                    \
            for (int bc = 0; bc < 4; ++bc)                                       \
                acc[t][bc] = __builtin_amdgcn_mfma_f32_16x16x32_bf16(            \
                    afr, bfr[bc], acc[t][bc], 0, 0, 0);                          \
        }                                                                        \
    }                                                                            \
} while (0)

    // Prologue: stage chunk 0 into buffer 0.
    STAGE(0);
    #pragma unroll
    for (int kc = 0; kc < NK - 1; ++kc) {
        STAGE((kc + 1) & 1);                              // next chunk in flight
        asm volatile("s_waitcnt vmcnt(8)" ::: "memory");  // cur chunk landed
        __builtin_amdgcn_s_barrier();                     // everyone's landed
        __builtin_amdgcn_sched_barrier(0);                // no hoisting across
        COMPUTE(kc & 1);
        __builtin_amdgcn_s_barrier();                     // readers done; buf free
    }
    asm volatile("s_waitcnt vmcnt(0)" ::: "memory");
    __builtin_amdgcn_s_barrier();
    __builtin_amdgcn_sched_barrier(0);
    COMPUTE((NK - 1) & 1);

    // Diagonal-of-pair geometry: wave (wr,wc) holds local rows
    // [wr*128, +128) x cols [wc*64, +64); the local diagonal (and the
    // pos diagonal on posblk) intersects iff wc>>1 == wr, at fragments
    // ar = (wc&1)*4 + d, bc = d, lanes cq == quad*4+reg.
    const int arb = (wc & 1) * 4;
    const bool ondiag = ((wc >> 1) == wr);

    // pos extraction BEFORE exp: logit (2*cos) = acc * ln2.
    if (posblk && ondiag) {
        #pragma unroll
        for (int d = 0; d < 4; ++d)
            #pragma unroll
            for (int reg = 0; reg < 4; ++reg)
                if (cq == quad * 4 + reg) {
                    int gr = rowbase + wr * 128 + (arb + d) * 16 + quad * 4 + reg;
                    pos_ws[gr] = acc[arb + d][d][reg] * LN2F;
                }
    }

    // exp2 is the native op: one v_exp_f32 per element.
    #pragma unroll
    for (int ar = 0; ar < 8; ++ar)
        #pragma unroll
        for (int bc = 0; bc < 4; ++bc)
            #pragma unroll
            for (int reg = 0; reg < 4; ++reg)
                acc[ar][bc][reg] = fast_exp2(acc[ar][bc][reg]);
    if (diagblk && ondiag) {
        #pragma unroll
        for (int d = 0; d < 4; ++d)
            #pragma unroll
            for (int reg = 0; reg < 4; ++reg)
                if (cq == quad * 4 + reg) acc[arb + d][d][reg] = 0.0f;
    }

    // ---- LDS overlay: rsum/csum reuse As buf0 (all K-loop readers done) ----
    float* rsum_lds = (float*)As;         // floats [0..255]
    float* csum_lds = rsum_lds + BM;      // floats [256..511]
    __syncthreads();                       // all waves past their LDS reads
    ((float*)As)[tid] = 0.0f;              // 512 floats = rsum + csum
    __syncthreads();

    // Row sums: sum over 16 cols (bc in-register, cq via shuffle).
    #pragma unroll
    for (int ar = 0; ar < 8; ++ar) {
        float rs[4];
        #pragma unroll
        for (int reg = 0; reg < 4; ++reg) {
            float v = acc[ar][0][reg] + acc[ar][1][reg] + acc[ar][2][reg] + acc[ar][3][reg];
            v += __shfl_xor(v, 1); v += __shfl_xor(v, 2);
            v += __shfl_xor(v, 4); v += __shfl_xor(v, 8);
            rs[reg] = v;
        }
        if (cq == 0) {
            #pragma unroll
            for (int reg = 0; reg < 4; ++reg)
                atomicAdd(&rsum_lds[wr * 128 + ar * 16 + quad * 4 + reg], rs[reg]);
        }
    }

    // Col sums (symmetry): only for off-diagonal blocks.
    if (!diagblk) {
        #pragma unroll
        for (int bc = 0; bc < 4; ++bc) {
            float cs = 0.0f;
            #pragma unroll
            for (int ar = 0; ar < 8; ++ar)
                #pragma unroll
                for (int reg = 0; reg < 4; ++reg)
                    cs += acc[ar][bc][reg];
            cs += __shfl_xor(cs, 16); cs += __shfl_xor(cs, 32);
            if (quad == 0) atomicAdd(&csum_lds[wc * 64 + bc * 16 + cq], cs);
        }
    }

    __syncthreads();
    if (tid < BM) atomicAdd(&rowsum[rowbase + tid], rsum_lds[tid]);
    else if (!diagblk) atomicAdd(&rowsum[colbase + tid - BM], csum_lds[tid - BM]);
#undef STAGE
#undef COMPUTE
}

// Kernel 3: single block. mean_r( log(rowsum[r]) - pos[r & (BHALF-1)] ).
__global__ __launch_bounds__(256) void finalize_kernel(
    const float* __restrict__ rowsum, const float* __restrict__ pos_ws,
    float* __restrict__ out)
{
    __shared__ float red[4];
    float s = 0.0f;
    for (int r = threadIdx.x; r < N_TOT; r += 256)
        s += __logf(rowsum[r]) - pos_ws[r & (BHALF - 1)];
    #pragma unroll
    for (int off = 1; off < 64; off <<= 1) s += __shfl_xor(s, off);
    int wave = threadIdx.x >> 6, lane = threadIdx.x & 63;
    if (lane == 0) red[wave] = s;
    __syncthreads();
    if (threadIdx.x == 0)
        out[0] = (red[0] + red[1] + red[2] + red[3]) * (1.0f / N_TOT);
}

extern "C" void kernel_launch(void* const* d_in, const int* in_sizes, int n_in,
                              void* d_out, int out_size, void* d_ws, size_t ws_size,
                              hipStream_t stream) {
    const float* zis = (const float*)d_in[0];
    const float* zjs = (const float*)d_in[1];
    float* rowsum = (float*)d_ws;                                   // 32 KB
    float* pos_ws = rowsum + N_TOT;                                 // 16 KB
    unsigned short* zb = (unsigned short*)(pos_ws + BHALF);         // 8 MB, 16B-aligned
    float* out = (float*)d_out;

    normalize_kernel<<<N_TOT / 4, 256, 0, stream>>>(zis, zjs, zb, rowsum);
    ntxent_tri_kernel<<<NBLOCKS, 512, 0, stream>>>(zb, rowsum, pos_ws);
    finalize_kernel<<<1, 256, 0, stream>>>(rowsum, pos_ws, out);
}

// Round 10
// 134.109 us; speedup vs baseline: 7.3382x; 7.3382x over previous
//
#include <hip/hip_runtime.h>

#define N_TOT 8192
#define BHALF 4096
#define D_DIM 512
#define BM 256            // block tile 256x256
#define NTILE 32          // N_TOT / BM
#define NBLOCKS 528       // NTILE*(NTILE+1)/2 upper-triangle tiles
#define TBK 64            // K per chunk (double-buffered)
#define NK 8              // D_DIM / TBK
#define PANEL (BM * TBK)  // 16384 bf16 elems = 32 KB per buffer

// Z is scaled by sqrt(2/ln2) at normalize time, so acc = (2/ln2)*cos and
// exp(2*cos) == exp2(acc) -> bare v_exp_f32 in the epilogue.
// The positive LOGIT (2*cos) is recovered as acc * ln2.
#define ZSCALE 1.69864368f      // sqrt(2/ln(2))
#define LN2F   0.69314718f

typedef float f32x4 __attribute__((ext_vector_type(4)));
typedef short s16x8 __attribute__((ext_vector_type(8)));  // 8 bf16 in 4 VGPRs

__device__ __forceinline__ unsigned short f2bf(float x) {
    union { float f; unsigned int u; } v; v.f = x;
    unsigned int lsb = (v.u >> 16) & 1u;
    unsigned int r = v.u + 0x7fffu + lsb;   // round-to-nearest-even
    return (unsigned short)(r >> 16);
}

__device__ __forceinline__ float fast_exp2(float x) {
#if __has_builtin(__builtin_amdgcn_exp2f)
    return __builtin_amdgcn_exp2f(x);
#else
    return exp2f(x);
#endif
}

// Kernel 1: row L2-normalize [zjs; zis] * ZSCALE -> bf16 Z.
// Blocks 0..31 zero rowsum.
__global__ __launch_bounds__(256) void normalize_kernel(
    const float* __restrict__ zis, const float* __restrict__ zjs,
    unsigned short* __restrict__ zb, float* __restrict__ rowsum)
{
    if (blockIdx.x < 32) rowsum[blockIdx.x * 256 + threadIdx.x] = 0.0f;
    int wave = threadIdx.x >> 6;
    int lane = threadIdx.x & 63;
    int row  = blockIdx.x * 4 + wave;
    const float* src = (row < BHALF) ? (zjs + (size_t)row * D_DIM)
                                     : (zis + (size_t)(row - BHALF) * D_DIM);
    const float4* src4 = (const float4*)src;
    float4 v0 = src4[lane * 2];
    float4 v1 = src4[lane * 2 + 1];
    float ss = v0.x*v0.x + v0.y*v0.y + v0.z*v0.z + v0.w*v0.w
             + v1.x*v1.x + v1.y*v1.y + v1.z*v1.z + v1.w*v1.w;
    #pragma unroll
    for (int off = 1; off < 64; off <<= 1) ss += __shfl_xor(ss, off);
    float scale = ZSCALE / fmaxf(sqrtf(ss), 1e-8f);

    float vals[8] = {v0.x, v0.y, v0.z, v0.w, v1.x, v1.y, v1.z, v1.w};
    unsigned short u[8];
    #pragma unroll
    for (int i = 0; i < 8; ++i) u[i] = f2bf(vals[i] * scale);
    uint4 o;
    o.x = u[0] | ((unsigned)u[1] << 16);
    o.y = u[2] | ((unsigned)u[3] << 16);
    o.z = u[4] | ((unsigned)u[5] << 16);
    o.w = u[6] | ((unsigned)u[7] << 16);
    ((uint4*)(zb + (size_t)row * D_DIM))[lane] = o;
}

// Kernel 2: upper-triangle 256x256 tiles of exp2(Zs.Zs^T), diag masked.
//
// ROUND 10 — same 256^2 / 8-wave geometry as R9, with the rule-#20 fix:
// R9's epilogue indexed acc[arb+d] with RUNTIME arb=(wc&1)*4 -> the whole
// acc[8][4] array was scratch-allocated (VGPR_Count 112 < 128 needed;
// WRITE_SIZE 2.36 GB of spill traffic; MfmaUtil 1.5%). Fix: branch on
// (wc&1) so every acc index is a compile-time constant after unroll.
// Geometry rationale (unchanged): wave tile 128x64 cuts LDS fragment-read
// bytes/FLOP 25% vs R6's 64x64 -- attacks the measured LDS-pipe bound.
//
// XCD-CHUNKED SWIZZLE (verified R6: FETCH 72.8->19.9 MB): 528 = 8*66,
// bijective; per-XCD concurrent panel set ~3 MB fits the 4 MB L2.
//
// LDS swizzle (128B rows, 8 x 16B units): unit for (row r, k-unit c8) is
// r*8 + (c8 ^ (r&7)). Staging dest linear in tid (global_load_lds
// requirement); global SOURCE pre-swizzled: c8 = (tid&7) ^ ((tid>>3)&7),
// invariant across rounds since rnd*64 = 0 (mod 8).
__global__ __launch_bounds__(512, 2) void ntxent_tri_kernel(
    const unsigned short* __restrict__ zb, float* __restrict__ rowsum,
    float* __restrict__ pos_ws)
{
    __shared__ unsigned short As[2 * PANEL];   // 64 KB (2 buffers)
    __shared__ unsigned short Bs[2 * PANEL];   // 64 KB
    // rsum/csum (512 floats) overlay onto As buf0 after the K-loop.

    const int tid  = threadIdx.x;
    const int wave = tid >> 6;
    const int lane = tid & 63;
    const int cq   = lane & 15;
    const int quad = lane >> 4;
    const int wr   = wave >> 2;    // wave row 0..1 (128 rows each)
    const int wc   = wave & 3;     // wave col 0..3 (64 cols each)

    // XCD-chunked bijective remap (528 = 8 * 66).
    const int swzbid = (blockIdx.x & 7) * (NBLOCKS / 8) + (blockIdx.x >> 3);

    // swzbid -> (I,J), J-group-major (8 J-panels/group), I-major in group.
    int g = 0, rem = swzbid;
    while (rem >= 64 * g + 36) { rem -= 64 * g + 36; ++g; }
    int I, J;
    if (rem < 64 * g) { I = rem >> 3; J = 8 * g + (rem & 7); }
    else {
        rem -= 64 * g;
        int ii = 0;
        while (rem >= 8 - ii) { rem -= 8 - ii; ++ii; }
        I = 8 * g + ii;
        J = I + rem;
    }
    const int rowbase = I * BM;
    const int colbase = J * BM;
    const bool diagblk = (I == J);
    const bool posblk  = (J == I + NTILE / 2);   // contains (i, i+BHALF) pairs

    // Staging: round rnd covers rows rnd*64 + (tid>>3); unit slot tid&7;
    // pre-swizzled global k-unit c8 = (tid&7) ^ ((tid>>3)&7).
    const int c8s = (tid & 7) ^ ((tid >> 3) & 7);
    const unsigned short* gA[4];
    const unsigned short* gB[4];
    #pragma unroll
    for (int rnd = 0; rnd < 4; ++rnd) {
        int r = rnd * 64 + (tid >> 3);
        gA[rnd] = zb + (size_t)(rowbase + r) * D_DIM + c8s * 8;
        gB[rnd] = zb + (size_t)(colbase + r) * D_DIM + c8s * 8;
    }

    // Fragment-read constants: row ra = wr*128 + t*16 + cq (A, t=0..7),
    // rb = wc*64 + t*16 + cq (B, t=0..3); ra&7 == rb&7 == cq&7.
    const int swzq = cq & 7;
    int aOff[8], bOff[4];
    #pragma unroll
    for (int t = 0; t < 8; ++t) aOff[t] = (wr * 128 + t * 16 + cq) * TBK;
    #pragma unroll
    for (int t = 0; t < 4; ++t) bOff[t] = (wc * 64 + t * 16 + cq) * TBK;

    f32x4 acc[8][4];
    #pragma unroll
    for (int a = 0; a < 8; ++a)
        #pragma unroll
        for (int b = 0; b < 4; ++b)
            acc[a][b] = (f32x4){0.f, 0.f, 0.f, 0.f};

#define STAGE(buf) do {                                                          \
    const int dbase = (buf) * PANEL;                                             \
    _Pragma("unroll")                                                            \
    for (int rnd = 0; rnd < 4; ++rnd) {                                          \
        __builtin_amdgcn_global_load_lds(                                        \
            (const __attribute__((address_space(1))) unsigned int*)gA[rnd],      \
            (__attribute__((address_space(3))) unsigned int*)                    \
                &As[dbase + rnd * 4096 + tid * 8], 16, 0, 0);                    \
        __builtin_amdgcn_global_load_lds(                                        \
            (const __attribute__((address_space(1))) unsigned int*)gB[rnd],      \
            (__attribute__((address_space(3))) unsigned int*)                    \
                &Bs[dbase + rnd * 4096 + tid * 8], 16, 0, 0);                    \
        gA[rnd] += TBK; gB[rnd] += TBK;                                          \
    }                                                                            \
} while (0)

#define COMPUTE(buf) do {                                                        \
    const int cbase = (buf) * PANEL;                                             \
    _Pragma("unroll")                                                            \
    for (int kk = 0; kk < 2; ++kk) {                                             \
        s16x8 bfr[4];                                                            \
        const int c8 = (kk << 2) | quad;                                         \
        _Pragma("unroll")                                                        \
        for (int t = 0; t < 4; ++t)                                              \
            bfr[t] = *(const s16x8*)&Bs[cbase + bOff[t] + ((c8 ^ swzq) << 3)];   \
        _Pragma("unroll")                                                        \
        for (int t = 0; t < 8; ++t) {                                            \
            s16x8 afr = *(const s16x8*)&As[cbase + aOff[t] + ((c8 ^ swzq) << 3)];\
            _Pragma("unroll")                                                    \
            for (int bc = 0; bc < 4; ++bc)                                       \
                acc[t][bc] = __builtin_amdgcn_mfma_f32_16x16x32_bf16(            \
                    afr, bfr[bc], acc[t][bc], 0, 0, 0);                          \
        }                                                                        \
    }                                                                            \
} while (0)

    // Prologue: stage chunk 0 into buffer 0.
    STAGE(0);
    #pragma unroll
    for (int kc = 0; kc < NK - 1; ++kc) {
        STAGE((kc + 1) & 1);                              // next chunk in flight
        asm volatile("s_waitcnt vmcnt(8)" ::: "memory");  // cur chunk landed
        __builtin_amdgcn_s_barrier();                     // everyone's landed
        __builtin_amdgcn_sched_barrier(0);                // no hoisting across
        COMPUTE(kc & 1);
        __builtin_amdgcn_s_barrier();                     // readers done; buf free
    }
    asm volatile("s_waitcnt vmcnt(0)" ::: "memory");
    __builtin_amdgcn_s_barrier();
    __builtin_amdgcn_sched_barrier(0);
    COMPUTE((NK - 1) & 1);

    // Diagonal-of-pair geometry: wave (wr,wc) holds local rows
    // [wr*128, +128) x cols [wc*64, +64); the (pos/self) diagonal intersects
    // iff wc>>1 == wr, at fragments ar = (wc&1)*4 + d, bc = d, lanes
    // cq == quad*4+reg. RULE #20: branch on (wc&1) so acc indices stay
    // compile-time constants (runtime arb scratch-allocated acc in R9).
    const bool ondiag = ((wc >> 1) == wr);

    // pos extraction BEFORE exp: logit (2*cos) = acc * ln2.
    if (posblk && ondiag) {
        if (wc & 1) {
            #pragma unroll
            for (int d = 0; d < 4; ++d)
                #pragma unroll
                for (int reg = 0; reg < 4; ++reg)
                    if (cq == quad * 4 + reg) {
                        int gr = rowbase + wr * 128 + (4 + d) * 16 + quad * 4 + reg;
                        pos_ws[gr] = acc[4 + d][d][reg] * LN2F;
                    }
        } else {
            #pragma unroll
            for (int d = 0; d < 4; ++d)
                #pragma unroll
                for (int reg = 0; reg < 4; ++reg)
                    if (cq == quad * 4 + reg) {
                        int gr = rowbase + wr * 128 + d * 16 + quad * 4 + reg;
                        pos_ws[gr] = acc[d][d][reg] * LN2F;
                    }
        }
    }

    // exp2 is the native op: one v_exp_f32 per element.
    #pragma unroll
    for (int ar = 0; ar < 8; ++ar)
        #pragma unroll
        for (int bc = 0; bc < 4; ++bc)
            #pragma unroll
            for (int reg = 0; reg < 4; ++reg)
                acc[ar][bc][reg] = fast_exp2(acc[ar][bc][reg]);
    if (diagblk && ondiag) {
        if (wc & 1) {
            #pragma unroll
            for (int d = 0; d < 4; ++d)
                #pragma unroll
                for (int reg = 0; reg < 4; ++reg)
                    if (cq == quad * 4 + reg) acc[4 + d][d][reg] = 0.0f;
        } else {
            #pragma unroll
            for (int d = 0; d < 4; ++d)
                #pragma unroll
                for (int reg = 0; reg < 4; ++reg)
                    if (cq == quad * 4 + reg) acc[d][d][reg] = 0.0f;
        }
    }

    // ---- LDS overlay: rsum/csum reuse As buf0 (all K-loop readers done) ----
    float* rsum_lds = (float*)As;         // floats [0..255]
    float* csum_lds = rsum_lds + BM;      // floats [256..511]
    __syncthreads();                       // all waves past their LDS reads
    ((float*)As)[tid] = 0.0f;              // 512 floats = rsum + csum
    __syncthreads();

    // Row sums: sum over 16 cols (bc in-register, cq via shuffle).
    #pragma unroll
    for (int ar = 0; ar < 8; ++ar) {
        float rs[4];
        #pragma unroll
        for (int reg = 0; reg < 4; ++reg) {
            float v = acc[ar][0][reg] + acc[ar][1][reg] + acc[ar][2][reg] + acc[ar][3][reg];
            v += __shfl_xor(v, 1); v += __shfl_xor(v, 2);
            v += __shfl_xor(v, 4); v += __shfl_xor(v, 8);
            rs[reg] = v;
        }
        if (cq == 0) {
            #pragma unroll
            for (int reg = 0; reg < 4; ++reg)
                atomicAdd(&rsum_lds[wr * 128 + ar * 16 + quad * 4 + reg], rs[reg]);
        }
    }

    // Col sums (symmetry): only for off-diagonal blocks.
    if (!diagblk) {
        #pragma unroll
        for (int bc = 0; bc < 4; ++bc) {
            float cs = 0.0f;
            #pragma unroll
            for (int ar = 0; ar < 8; ++ar)
                #pragma unroll
                for (int reg = 0; reg < 4; ++reg)
                    cs += acc[ar][bc][reg];
            cs += __shfl_xor(cs, 16); cs += __shfl_xor(cs, 32);
            if (quad == 0) atomicAdd(&csum_lds[wc * 64 + bc * 16 + cq], cs);
        }
    }

    __syncthreads();
    if (tid < BM) atomicAdd(&rowsum[rowbase + tid], rsum_lds[tid]);
    else if (!diagblk) atomicAdd(&rowsum[colbase + tid - BM], csum_lds[tid - BM]);
#undef STAGE
#undef COMPUTE
}

// Kernel 3: single block. mean_r( log(rowsum[r]) - pos[r & (BHALF-1)] ).
__global__ __launch_bounds__(256) void finalize_kernel(
    const float* __restrict__ rowsum, const float* __restrict__ pos_ws,
    float* __restrict__ out)
{
    __shared__ float red[4];
    float s = 0.0f;
    for (int r = threadIdx.x; r < N_TOT; r += 256)
        s += __logf(rowsum[r]) - pos_ws[r & (BHALF - 1)];
    #pragma unroll
    for (int off = 1; off < 64; off <<= 1) s += __shfl_xor(s, off);
    int wave = threadIdx.x >> 6, lane = threadIdx.x & 63;
    if (lane == 0) red[wave] = s;
    __syncthreads();
    if (threadIdx.x == 0)
        out[0] = (red[0] + red[1] + red[2] + red[3]) * (1.0f / N_TOT);
}

extern "C" void kernel_launch(void* const* d_in, const int* in_sizes, int n_in,
                              void* d_out, int out_size, void* d_ws, size_t ws_size,
                              hipStream_t stream) {
    const float* zis = (const float*)d_in[0];
    const float* zjs = (const float*)d_in[1];
    float* rowsum = (float*)d_ws;                                   // 32 KB
    float* pos_ws = rowsum + N_TOT;                                 // 16 KB
    unsigned short* zb = (unsigned short*)(pos_ws + BHALF);         // 8 MB, 16B-aligned
    float* out = (float*)d_out;

    normalize_kernel<<<N_TOT / 4, 256, 0, stream>>>(zis, zjs, zb, rowsum);
    ntxent_tri_kernel<<<NBLOCKS, 512, 0, stream>>>(zb, rowsum, pos_ws);
    finalize_kernel<<<1, 256, 0, stream>>>(rowsum, pos_ws, out);
}

// Round 11
// 124.127 us; speedup vs baseline: 7.9283x; 1.0804x over previous
//
#include <hip/hip_runtime.h>

#define N_TOT 8192
#define BHALF 4096
#define D_DIM 512
#define BM 128
#define NTILE 64          // N_TOT / BM
#define NBLOCKS 2080      // NTILE*(NTILE+1)/2 upper-triangle tiles
#define BK2 32            // K per chunk
#define NCHUNK 16         // D_DIM / BK2
#define BUFSZ (BM * BK2)  // 4096 bf16 elems = 8 KB per buffer
#define NBUF 3            // triple buffer: 2-deep prefetch

// Z is scaled by sqrt(2/ln2) at normalize time, so acc = (2/ln2)*cos and
// exp(2*cos) == exp2(acc) -> bare v_exp_f32 in the epilogue.
// The positive LOGIT (2*cos) is recovered as acc * ln2.
#define ZSCALE 1.69864368f      // sqrt(2/ln(2))
#define LN2F   0.69314718f

typedef float f32x4 __attribute__((ext_vector_type(4)));
typedef short s16x8 __attribute__((ext_vector_type(8)));  // 8 bf16 in 4 VGPRs

__device__ __forceinline__ unsigned short f2bf(float x) {
    union { float f; unsigned int u; } v; v.f = x;
    unsigned int lsb = (v.u >> 16) & 1u;
    unsigned int r = v.u + 0x7fffu + lsb;   // round-to-nearest-even
    return (unsigned short)(r >> 16);
}

__device__ __forceinline__ float fast_exp2(float x) {
#if __has_builtin(__builtin_amdgcn_exp2f)
    return __builtin_amdgcn_exp2f(x);
#else
    return exp2f(x);
#endif
}

// Kernel 1: row L2-normalize [zjs; zis] * ZSCALE -> bf16 Z.
// Blocks 0..31 zero rowsum.
__global__ __launch_bounds__(256) void normalize_kernel(
    const float* __restrict__ zis, const float* __restrict__ zjs,
    unsigned short* __restrict__ zb, float* __restrict__ rowsum)
{
    if (blockIdx.x < 32) rowsum[blockIdx.x * 256 + threadIdx.x] = 0.0f;
    int wave = threadIdx.x >> 6;
    int lane = threadIdx.x & 63;
    int row  = blockIdx.x * 4 + wave;
    const float* src = (row < BHALF) ? (zjs + (size_t)row * D_DIM)
                                     : (zis + (size_t)(row - BHALF) * D_DIM);
    const float4* src4 = (const float4*)src;
    float4 v0 = src4[lane * 2];
    float4 v1 = src4[lane * 2 + 1];
    float ss = v0.x*v0.x + v0.y*v0.y + v0.z*v0.z + v0.w*v0.w
             + v1.x*v1.x + v1.y*v1.y + v1.z*v1.z + v1.w*v1.w;
    #pragma unroll
    for (int off = 1; off < 64; off <<= 1) ss += __shfl_xor(ss, off);
    float scale = ZSCALE / fmaxf(sqrtf(ss), 1e-8f);

    float vals[8] = {v0.x, v0.y, v0.z, v0.w, v1.x, v1.y, v1.z, v1.w};
    unsigned short u[8];
    #pragma unroll
    for (int i = 0; i < 8; ++i) u[i] = f2bf(vals[i] * scale);
    uint4 o;
    o.x = u[0] | ((unsigned)u[1] << 16);
    o.y = u[2] | ((unsigned)u[3] << 16);
    o.z = u[4] | ((unsigned)u[5] << 16);
    o.w = u[6] | ((unsigned)u[7] << 16);
    ((uint4*)(zb + (size_t)row * D_DIM))[lane] = o;
}

// Kernel 2: upper-triangle 128x128 tiles of exp2(Zs.Zs^T), diag masked.
//
// ROUND 11 — R6 chassis (best verified, 55.1us) + TRIPLE BUFFER (2-deep
// prefetch). R6's chunk loads get only ~1 COMPUTE (~150-250cy) before their
// vmcnt(4) wait -- marginal vs ~200-300cy L2 latency. 2-deep gives >=2
// compute phases of slack. Counted waits (m135: vmcnt(N) = wait until <=N
// outstanding): steady kc: issue chunk kc+2 (4 loads; 12 out), need chunk
// kc's oldest 4 done -> vmcnt(8); kc=14: 8 out, vmcnt(4); kc=15: vmcnt(0).
// Buffer reuse safe: STAGE((kc+2)%3) overwrites the buffer whose readers
// all passed iteration kc-1's trailing s_barrier. Full unroll keeps all
// buffer indices compile-time (rule #20). Cost: LDS 48 KB -> 3 blocks/CU
// (12 waves/CU vs R6's 16; VGPR-80 permits).
// 256^2 geometry rejected (R10: 60.2us -- 1 block/CU can't hide epilogue).
// setprio rejected (R7: +3.7us). Direct-global rejected (R8: 2.5x).
//
// XCD-CHUNKED SWIZZLE (verified R6: FETCH 72.8->19.9 MB): chunked bijective
// remap gives each XCD a contiguous 260-block range -> ~3.5 MB fits L2.
//
// LDS swizzle (64B rows): 16B unit for (row r, k-unit c8) lives at unit
// r*4 + (c8 ^ ((r>>1)&3)); fragment reads hit 8 distinct 16B slots per
// 16 lanes -> 2-way aliasing (free). Staging dest linear in tid
// (global_load_lds requirement); global SOURCE address pre-swizzled.
__global__ __launch_bounds__(256) void ntxent_tri_kernel(
    const unsigned short* __restrict__ zb, float* __restrict__ rowsum,
    float* __restrict__ pos_ws)
{
    __shared__ unsigned short As[NBUF * BUFSZ];   // 24 KB (3 buffers)
    __shared__ unsigned short Bs[NBUF * BUFSZ];   // 24 KB
    // rsum/csum overlay onto As after the K-loop -> total LDS 48 KB.

    const int tid  = threadIdx.x;
    const int wave = tid >> 6;
    const int lane = tid & 63;
    const int cq   = lane & 15;
    const int quad = lane >> 4;
    const int wr   = wave >> 1;    // wave row 0..1
    const int wc   = wave & 1;     // wave col 0..1

    // XCD-chunked bijective remap: wg i lands on XCD i%8 (round-robin HW
    // dispatch); give each XCD a contiguous 260-block range of the schedule.
    const int swzbid = (blockIdx.x & 7) * (NBLOCKS / 8) + (blockIdx.x >> 3);

    // swzbid -> (I,J), J-group-major (8 J-panels/group), I-major in group.
    int g = 0, rem = swzbid;
    while (rem >= 64 * g + 36) { rem -= 64 * g + 36; ++g; }
    int I, J;
    if (rem < 64 * g) { I = rem >> 3; J = 8 * g + (rem & 7); }
    else {
        rem -= 64 * g;
        int ii = 0;
        while (rem >= 8 - ii) { rem -= 8 - ii; ++ii; }
        I = 8 * g + ii;
        J = I + rem;
    }
    const int rowbase = I * BM;
    const int colbase = J * BM;
    const bool diagblk = (I == J);
    const bool posblk  = (J == I + NTILE / 2);   // contains (i, i+BHALF) pairs

    // Staging: thread tid, round rnd covers row r = rnd*64 + (tid>>2),
    // LDS unit u = tid&3. The global k-unit that belongs there is
    // c8 = u ^ ((r>>1)&3) = (tid&3) ^ ((tid>>3)&3)  (rnd-invariant).
    const int c8s = (tid & 3) ^ ((tid >> 3) & 3);
    const unsigned short* pA0 = zb + (size_t)(rowbase + (tid >> 2)) * D_DIM + c8s * 8;
    const unsigned short* pA1 = pA0 + (size_t)64 * D_DIM;
    const unsigned short* pB0 = zb + (size_t)(colbase + (tid >> 2)) * D_DIM + c8s * 8;
    const unsigned short* pB1 = pB0 + (size_t)64 * D_DIM;
    const int dst0 = tid * 8;            // elems; round 0
    const int dst1 = (256 + tid) * 8;    // elems; round 1

    // Fragment reads: lane wants k-unit 'quad' of row ra; it lives at LDS
    // unit u = quad ^ ((ra>>1)&3) = quad ^ ((cq>>1)&3)  (t/wr-invariant).
    const int swz = (quad ^ ((cq >> 1) & 3)) << 3;   // elem offset in row
    int aOff[4], bOff[4];
    #pragma unroll
    for (int t = 0; t < 4; ++t) {
        aOff[t] = (wr * 64 + t * 16 + cq) * BK2 + swz;
        bOff[t] = (wc * 64 + t * 16 + cq) * BK2 + swz;
    }

    f32x4 acc[4][4];
    #pragma unroll
    for (int a = 0; a < 4; ++a)
        #pragma unroll
        for (int b = 0; b < 4; ++b)
            acc[a][b] = (f32x4){0.f, 0.f, 0.f, 0.f};

#define STAGE(buf) do {                                                          \
    const int dbase = (buf) * BUFSZ;                                             \
    __builtin_amdgcn_global_load_lds(                                            \
        (const __attribute__((address_space(1))) unsigned int*)pA0,              \
        (__attribute__((address_space(3))) unsigned int*)&As[dbase + dst0],      \
        16, 0, 0);                                                               \
    __builtin_amdgcn_global_load_lds(                                            \
        (const __attribute__((address_space(1))) unsigned int*)pA1,              \
        (__attribute__((address_space(3))) unsigned int*)&As[dbase + dst1],      \
        16, 0, 0);                                                               \
    __builtin_amdgcn_global_load_lds(                                            \
        (const __attribute__((address_space(1))) unsigned int*)pB0,              \
        (__attribute__((address_space(3))) unsigned int*)&Bs[dbase + dst0],      \
        16, 0, 0);                                                               \
    __builtin_amdgcn_global_load_lds(                                            \
        (const __attribute__((address_space(1))) unsigned int*)pB1,              \
        (__attribute__((address_space(3))) unsigned int*)&Bs[dbase + dst1],      \
        16, 0, 0);                                                               \
    pA0 += BK2; pA1 += BK2; pB0 += BK2; pB1 += BK2;                              \
} while (0)

#define COMPUTE(buf) do {                                                        \
    const int cbase = (buf) * BUFSZ;                                             \
    s16x8 af[4], bf[4];                                                          \
    _Pragma("unroll")                                                            \
    for (int t = 0; t < 4; ++t) {                                                \
        af[t] = *(const s16x8*)&As[cbase + aOff[t]];                             \
        bf[t] = *(const s16x8*)&Bs[cbase + bOff[t]];                             \
    }                                                                            \
    _Pragma("unroll")                                                            \
    for (int ar = 0; ar < 4; ++ar)                                               \
        _Pragma("unroll")                                                        \
        for (int bc = 0; bc < 4; ++bc)                                           \
            acc[ar][bc] = __builtin_amdgcn_mfma_f32_16x16x32_bf16(               \
                af[ar], bf[bc], acc[ar][bc], 0, 0, 0);                           \
} while (0)

    // Prologue: stage chunks 0,1 into buffers 0,1 (8 loads in flight).
    STAGE(0);
    STAGE(1);
    #pragma unroll
    for (int kc = 0; kc < NCHUNK; ++kc) {
        if (kc + 2 < NCHUNK) STAGE((kc + 2) % NBUF);      // 2-deep prefetch
        if (kc < NCHUNK - 2)
            asm volatile("s_waitcnt vmcnt(8)" ::: "memory");   // chunk kc landed
        else if (kc == NCHUNK - 2)
            asm volatile("s_waitcnt vmcnt(4)" ::: "memory");
        else
            asm volatile("s_waitcnt vmcnt(0)" ::: "memory");
        __builtin_amdgcn_s_barrier();                     // everyone's landed
        __builtin_amdgcn_sched_barrier(0);                // no hoisting across
        COMPUTE(kc % NBUF);
        __builtin_amdgcn_s_barrier();                     // readers done; buf free
    }

    // pos extraction BEFORE exp: gc == gr + BHALF  <=>  wc==wr, bc==ar, cq==quad*4+reg
    // acc = (2/ln2)*cos -> logit (2*cos) = acc * ln2. Plain store: the separate
    // finalize kernel launch is the synchronization point.
    if (posblk && wc == wr) {
        #pragma unroll
        for (int ar = 0; ar < 4; ++ar)
            #pragma unroll
            for (int reg = 0; reg < 4; ++reg)
                if (cq == quad * 4 + reg) {
                    int gr = rowbase + wr * 64 + ar * 16 + quad * 4 + reg;
                    pos_ws[gr] = acc[ar][ar][reg] * LN2F;
                }
    }

    // exp2 is the native op: one v_exp_f32 per element.
    #pragma unroll
    for (int ar = 0; ar < 4; ++ar)
        #pragma unroll
        for (int bc = 0; bc < 4; ++bc)
            #pragma unroll
            for (int reg = 0; reg < 4; ++reg)
                acc[ar][bc][reg] = fast_exp2(acc[ar][bc][reg]);
    if (diagblk && wr == wc) {
        #pragma unroll
        for (int ar = 0; ar < 4; ++ar)
            #pragma unroll
            for (int reg = 0; reg < 4; ++reg)
                if (cq == quad * 4 + reg) acc[ar][ar][reg] = 0.0f;
    }

    // ---- LDS overlay: rsum/csum reuse As (K-loop readers all done) ----
    float* rsum_lds = (float*)As;         // floats [0..127]
    float* csum_lds = rsum_lds + BM;      // floats [128..255]
    __syncthreads();                       // all waves past their LDS reads
    ((float*)As)[tid] = 0.0f;              // 256 floats = rsum + csum
    __syncthreads();

    // Row sums: sum over 16 cols (bc in-register, cq via shuffle).
    #pragma unroll
    for (int ar = 0; ar < 4; ++ar) {
        float rs[4];
        #pragma unroll
        for (int reg = 0; reg < 4; ++reg) {
            float v = acc[ar][0][reg] + acc[ar][1][reg] + acc[ar][2][reg] + acc[ar][3][reg];
            v += __shfl_xor(v, 1); v += __shfl_xor(v, 2);
            v += __shfl_xor(v, 4); v += __shfl_xor(v, 8);
            rs[reg] = v;
        }
        if (cq == 0) {
            #pragma unroll
            for (int reg = 0; reg < 4; ++reg)
                atomicAdd(&rsum_lds[wr * 64 + ar * 16 + quad * 4 + reg], rs[reg]);
        }
    }

    // Col sums (symmetry): only for off-diagonal blocks.
    if (!diagblk) {
        #pragma unroll
        for (int bc = 0; bc < 4; ++bc) {
            float cs = 0.0f;
            #pragma unroll
            for (int ar = 0; ar < 4; ++ar)
                #pragma unroll
                for (int reg = 0; reg < 4; ++reg)
                    cs += acc[ar][bc][reg];
            cs += __shfl_xor(cs, 16); cs += __shfl_xor(cs, 32);
            if (quad == 0) atomicAdd(&csum_lds[wc * 64 + bc * 16 + cq], cs);
        }
    }

    __syncthreads();
    if (tid < BM) atomicAdd(&rowsum[rowbase + tid], rsum_lds[tid]);
    else if (!diagblk) atomicAdd(&rowsum[colbase + tid - BM], csum_lds[tid - BM]);
#undef STAGE
#undef COMPUTE
}

// Kernel 3: single block. mean_r( log(rowsum[r]) - pos[r & (BHALF-1)] ).
__global__ __launch_bounds__(256) void finalize_kernel(
    const float* __restrict__ rowsum, const float* __restrict__ pos_ws,
    float* __restrict__ out)
{
    __shared__ float red[4];
    float s = 0.0f;
    for (int r = threadIdx.x; r < N_TOT; r += 256)
        s += __logf(rowsum[r]) - pos_ws[r & (BHALF - 1)];
    #pragma unroll
    for (int off = 1; off < 64; off <<= 1) s += __shfl_xor(s, off);
    int wave = threadIdx.x >> 6, lane = threadIdx.x & 63;
    if (lane == 0) red[wave] = s;
    __syncthreads();
    if (threadIdx.x == 0)
        out[0] = (red[0] + red[1] + red[2] + red[3]) * (1.0f / N_TOT);
}

extern "C" void kernel_launch(void* const* d_in, const int* in_sizes, int n_in,
                              void* d_out, int out_size, void* d_ws, size_t ws_size,
                              hipStream_t stream) {
    const float* zis = (const float*)d_in[0];
    const float* zjs = (const float*)d_in[1];
    float* rowsum = (float*)d_ws;                                   // 32 KB
    float* pos_ws = rowsum + N_TOT;                                 // 16 KB
    unsigned short* zb = (unsigned short*)(pos_ws + BHALF);         // 8 MB, 16B-aligned
    float* out = (float*)d_out;

    normalize_kernel<<<N_TOT / 4, 256, 0, stream>>>(zis, zjs, zb, rowsum);
    ntxent_tri_kernel<<<NBLOCKS, 256, 0, stream>>>(zb, rowsum, pos_ws);
    finalize_kernel<<<1, 256, 0, stream>>>(rowsum, pos_ws, out);
}

// Round 12
// 122.435 us; speedup vs baseline: 8.0379x; 1.0138x over previous
//
#include <hip/hip_runtime.h>

#define N_TOT 8192
#define BHALF 4096
#define D_DIM 512
#define BM 128
#define NTILE 64          // N_TOT / BM
#define NBLOCKS 2080      // NTILE*(NTILE+1)/2 upper-triangle tiles
#define BKQ 64            // K per chunk (fp8: 64 B rows)
#define NCHUNK 8          // D_DIM / BKQ
#define BUFS 4096         // shorts per buffer (128 rows x 64 B = 8 KB)
#define NBUF 3            // triple buffer: 2-deep prefetch (R11-proven)

// Q = e4m3(256 * z/||z||). corr[r] = ZSCALE/||Q_r|| (exact f32). Then
// acc*cr*cc = (2/ln2)*cos(Q_i,Q_j) exactly -> exp2() is exp(2*cos), and the
// pos LOGIT (2*cos) = corrected * ln2. Norm correction kills the systematic
// quantization-energy bias (+E[eps^2] in ||Q||) that would shift the loss.
#define ZSCALE 1.69864368f      // sqrt(2/ln(2))
#define LN2F   0.69314718f
#define SCALE_Q 256.0f          // exact power of 2: rescues subnormals, no overflow

typedef float f32x4 __attribute__((ext_vector_type(4)));
typedef long long i64;

// ---- hand-rolled OCP e4m3fn converters (no header-API dependency) ----
__device__ __forceinline__ unsigned int f2e4m3(float x) {
    union { float f; unsigned u; } v; v.f = x;
    unsigned a = v.u & 0x7fffffffu;
    unsigned s = (v.u >> 24) & 0x80u;
    unsigned m;
    if (a < 0x3C800000u) {                       // |x| < 2^-6 -> subnormal
        union { unsigned u; float f; } w; w.u = a;
        m = (unsigned)(w.f * 512.0f + 0.5f);     // 0..8 (8 == 0x08 == 2^-6 exactly)
    } else {                                     // normal, RNE to 3 mantissa bits
        unsigned r = a + 0x7FFFFu + ((a >> 20) & 1u);
        unsigned e8 = (r >> 23) - 120u;          // 1..15 for |x| <= 256
        m = (e8 << 3) | ((r >> 20) & 7u);
    }
    return s | m;
}
__device__ __forceinline__ float e4m32f(unsigned b) {
    unsigned e = (b >> 3) & 15u, m = b & 7u;
    float v;
    if (e) { union { unsigned u; float f; } w; w.u = ((e + 120u) << 23) | (m << 20); v = w.f; }
    else v = (float)m * 0x1p-9f;
    return (b & 0x80u) ? -v : v;
}

__device__ __forceinline__ float fast_exp2(float x) {
#if __has_builtin(__builtin_amdgcn_exp2f)
    return __builtin_amdgcn_exp2f(x);
#else
    return exp2f(x);
#endif
}

// Kernel 1: row L2-normalize [zjs; zis], quantize to e4m3 (x256), store
// per-row exact norm correction. Blocks 0..31 zero rowsum.
__global__ __launch_bounds__(256) void normalize_kernel(
    const float* __restrict__ zis, const float* __restrict__ zjs,
    unsigned char* __restrict__ zq, float* __restrict__ corr,
    float* __restrict__ rowsum)
{
    if (blockIdx.x < 32) rowsum[blockIdx.x * 256 + threadIdx.x] = 0.0f;
    int wave = threadIdx.x >> 6;
    int lane = threadIdx.x & 63;
    int row  = blockIdx.x * 4 + wave;
    const float* src = (row < BHALF) ? (zjs + (size_t)row * D_DIM)
                                     : (zis + (size_t)(row - BHALF) * D_DIM);
    const float4* src4 = (const float4*)src;
    float4 v0 = src4[lane * 2];
    float4 v1 = src4[lane * 2 + 1];
    float ss = v0.x*v0.x + v0.y*v0.y + v0.z*v0.z + v0.w*v0.w
             + v1.x*v1.x + v1.y*v1.y + v1.z*v1.z + v1.w*v1.w;
    #pragma unroll
    for (int off = 1; off < 64; off <<= 1) ss += __shfl_xor(ss, off);
    float scale = SCALE_Q / fmaxf(sqrtf(ss), 1e-8f);

    float vals[8] = {v0.x, v0.y, v0.z, v0.w, v1.x, v1.y, v1.z, v1.w};
    unsigned b[8]; float ssq = 0.0f;
    #pragma unroll
    for (int i = 0; i < 8; ++i) {
        b[i] = f2e4m3(vals[i] * scale);
        float d = e4m32f(b[i]);
        ssq += d * d;
    }
    #pragma unroll
    for (int off = 1; off < 64; off <<= 1) ssq += __shfl_xor(ssq, off);

    uint2 o;
    o.x = b[0] | (b[1] << 8) | (b[2] << 16) | (b[3] << 24);
    o.y = b[4] | (b[5] << 8) | (b[6] << 16) | (b[7] << 24);
    ((uint2*)(zq + (size_t)row * D_DIM))[lane] = o;
    if (lane == 0) corr[row] = ZSCALE / fmaxf(sqrtf(ssq), 1e-8f);
}

// Kernel 2: upper-triangle 128x128 tiles of exp2(corr-scaled Q.Q^T).
//
// ROUND 12 — FP8 K-loop on the R11 chassis (triple-buffer, counted vmcnt,
// XCD swizzle). R7/R8/R10/R11 established the kernel is LDS-BYTE-bound
// (~9k LDS-pipe cyc/block vs 1.2k MFMA); fp8 halves fragment reads
// (512->256 KB/block, b128->b64), staging (256->128 KB) and FETCH. MFMA
// rate unchanged (non-scaled fp8 = bf16 rate). BKQ=64 -> 8 chunks, half
// the barriers; LDS stays 48 KB (3 buf x 8 KB x {A,B}).
//
// LDS swizzle (64 B fp8 rows, 8x 8B units): stored unit u_st = u ^ s(r),
// s(r) = 2*((r>>1)&3) (EVEN -> preserves 16 B staging pairs; a 16 B
// global_load_lds block stays contiguous+ordered). Fragment ds_read_b64:
// bank = 16*(r&1) + 2*(u^s) -> 8 distinct bank-pairs / 16 lanes, uniform
// 4 accesses/bank = the b64 floor (conflict-free). Staging source
// pre-swizzle in 16 B pairs: c16 = (t&3) ^ ((t>>3)&3), rnd-invariant.
//
// XCD-CHUNKED SWIZZLE (verified R6: FETCH 72.8->19.9 MB) unchanged.
__global__ __launch_bounds__(256) void ntxent_tri_kernel(
    const unsigned char* __restrict__ zq, const float* __restrict__ corr,
    float* __restrict__ rowsum, float* __restrict__ pos_ws)
{
    __shared__ unsigned short As[NBUF * BUFS];   // 24 KB (3 buffers)
    __shared__ unsigned short Bs[NBUF * BUFS];   // 24 KB
    // rsum/csum overlay onto As after the K-loop -> total LDS 48 KB.

    const int tid  = threadIdx.x;
    const int wave = tid >> 6;
    const int lane = tid & 63;
    const int cq   = lane & 15;
    const int quad = lane >> 4;
    const int wr   = wave >> 1;    // wave row 0..1
    const int wc   = wave & 1;     // wave col 0..1

    // XCD-chunked bijective remap (2080 = 8 * 260).
    const int swzbid = (blockIdx.x & 7) * (NBLOCKS / 8) + (blockIdx.x >> 3);

    // swzbid -> (I,J), J-group-major (8 J-panels/group), I-major in group.
    int g = 0, rem = swzbid;
    while (rem >= 64 * g + 36) { rem -= 64 * g + 36; ++g; }
    int I, J;
    if (rem < 64 * g) { I = rem >> 3; J = 8 * g + (rem & 7); }
    else {
        rem -= 64 * g;
        int ii = 0;
        while (rem >= 8 - ii) { rem -= 8 - ii; ++ii; }
        I = 8 * g + ii;
        J = I + rem;
    }
    const int rowbase = I * BM;
    const int colbase = J * BM;
    const bool diagblk = (I == J);
    const bool posblk  = (J == I + NTILE / 2);   // contains (i, i+BHALF) pairs

    // Staging: thread t, round rnd covers row r = rnd*64 + (t>>2), 16B-pair
    // p = t&3. Stored pair p holds global pair p ^ ((r>>1)&3) = (t&3)^((t>>3)&3).
    const int c16 = (tid & 3) ^ ((tid >> 3) & 3);
    const unsigned char* pA0 = zq + (size_t)(rowbase + (tid >> 2)) * D_DIM + c16 * 16;
    const unsigned char* pA1 = pA0 + (size_t)64 * D_DIM;
    const unsigned char* pB0 = zq + (size_t)(colbase + (tid >> 2)) * D_DIM + c16 * 16;
    const unsigned char* pB1 = pB0 + (size_t)64 * D_DIM;
    const int dst0 = tid * 8;            // shorts; round 0
    const int dst1 = 2048 + tid * 8;     // shorts; round 1

    // Fragment reads (ds_read_b64): row ra = wr*64+t*16+cq; s(ra) = 2*((cq>>1)&3).
    const int s2q = 2 * ((cq >> 1) & 3);
    int aOffS[4], bOffS[4];              // short offsets of row starts
    #pragma unroll
    for (int t = 0; t < 4; ++t) {
        aOffS[t] = (wr * 64 + t * 16 + cq) * 32;
        bOffS[t] = (wc * 64 + t * 16 + cq) * 32;
    }

    f32x4 acc[4][4];
    #pragma unroll
    for (int a = 0; a < 4; ++a)
        #pragma unroll
        for (int b = 0; b < 4; ++b)
            acc[a][b] = (f32x4){0.f, 0.f, 0.f, 0.f};

#define STAGE(buf) do {                                                          \
    const int dbase = (buf) * BUFS;                                              \
    __builtin_amdgcn_global_load_lds(                                            \
        (const __attribute__((address_space(1))) unsigned int*)pA0,              \
        (__attribute__((address_space(3))) unsigned int*)&As[dbase + dst0],      \
        16, 0, 0);                                                               \
    __builtin_amdgcn_global_load_lds(                                            \
        (const __attribute__((address_space(1))) unsigned int*)pA1,              \
        (__attribute__((address_space(3))) unsigned int*)&As[dbase + dst1],      \
        16, 0, 0);                                                               \
    __builtin_amdgcn_global_load_lds(                                            \
        (const __attribute__((address_space(1))) unsigned int*)pB0,              \
        (__attribute__((address_space(3))) unsigned int*)&Bs[dbase + dst0],      \
        16, 0, 0);                                                               \
    __builtin_amdgcn_global_load_lds(                                            \
        (const __attribute__((address_space(1))) unsigned int*)pB1,              \
        (__attribute__((address_space(3))) unsigned int*)&Bs[dbase + dst1],      \
        16, 0, 0);                                                               \
    pA0 += BKQ; pA1 += BKQ; pB0 += BKQ; pB1 += BKQ;                              \
} while (0)

#define COMPUTE(buf) do {                                                        \
    const int cbase = (buf) * BUFS;                                              \
    _Pragma("unroll")                                                            \
    for (int kk = 0; kk < 2; ++kk) {                                             \
        const int ko = ((((kk << 2) | quad) ^ s2q) << 2);   /* shorts */         \
        i64 af[4], bf[4];                                                        \
        _Pragma("unroll")                                                        \
        for (int t = 0; t < 4; ++t) {                                            \
            af[t] = *(const i64*)&As[cbase + aOffS[t] + ko];                     \
            bf[t] = *(const i64*)&Bs[cbase + bOffS[t] + ko];                     \
        }                                                                        \
        _Pragma("unroll")                                                        \
        for (int ar = 0; ar < 4; ++ar)                                           \
            _Pragma("unroll")                                                    \
            for (int bc = 0; bc < 4; ++bc)                                       \
                acc[ar][bc] = __builtin_amdgcn_mfma_f32_16x16x32_fp8_fp8(        \
                    af[ar], bf[bc], acc[ar][bc], 0, 0, 0);                       \
    }                                                                            \
} while (0)

    // Prologue: stage chunks 0,1 into buffers 0,1 (8 loads in flight).
    STAGE(0);
    STAGE(1);
    #pragma unroll
    for (int kc = 0; kc < NCHUNK; ++kc) {
        if (kc + 2 < NCHUNK) STAGE((kc + 2) % NBUF);      // 2-deep prefetch
        if (kc < NCHUNK - 2)
            asm volatile("s_waitcnt vmcnt(8)" ::: "memory");   // chunk kc landed
        else if (kc == NCHUNK - 2)
            asm volatile("s_waitcnt vmcnt(4)" ::: "memory");
        else
            asm volatile("s_waitcnt vmcnt(0)" ::: "memory");
        __builtin_amdgcn_s_barrier();                     // everyone's landed
        __builtin_amdgcn_sched_barrier(0);                // no hoisting across
        COMPUTE(kc % NBUF);
        __builtin_amdgcn_s_barrier();                     // readers done; buf free
    }

    // ---- exact norm correction: acc *= cr*cc -> (2/ln2)*cos(Q_i,Q_j) ----
    float cr[4][4], cc[4];
    #pragma unroll
    for (int ar = 0; ar < 4; ++ar)
        #pragma unroll
        for (int reg = 0; reg < 4; ++reg)
            cr[ar][reg] = corr[rowbase + wr * 64 + ar * 16 + quad * 4 + reg];
    #pragma unroll
    for (int bc = 0; bc < 4; ++bc)
        cc[bc] = corr[colbase + wc * 64 + bc * 16 + cq];
    #pragma unroll
    for (int ar = 0; ar < 4; ++ar)
        #pragma unroll
        for (int bc = 0; bc < 4; ++bc)
            #pragma unroll
            for (int reg = 0; reg < 4; ++reg)
                acc[ar][bc][reg] *= cr[ar][reg] * cc[bc];

    // pos extraction AFTER corr, BEFORE exp: logit (2*cos) = acc * ln2.
    if (posblk && wc == wr) {
        #pragma unroll
        for (int ar = 0; ar < 4; ++ar)
            #pragma unroll
            for (int reg = 0; reg < 4; ++reg)
                if (cq == quad * 4 + reg) {
                    int gr = rowbase + wr * 64 + ar * 16 + quad * 4 + reg;
                    pos_ws[gr] = acc[ar][ar][reg] * LN2F;
                }
    }

    // exp2 is the native op: one v_exp_f32 per element.
    #pragma unroll
    for (int ar = 0; ar < 4; ++ar)
        #pragma unroll
        for (int bc = 0; bc < 4; ++bc)
            #pragma unroll
            for (int reg = 0; reg < 4; ++reg)
                acc[ar][bc][reg] = fast_exp2(acc[ar][bc][reg]);
    if (diagblk && wr == wc) {
        #pragma unroll
        for (int ar = 0; ar < 4; ++ar)
            #pragma unroll
            for (int reg = 0; reg < 4; ++reg)
                if (cq == quad * 4 + reg) acc[ar][ar][reg] = 0.0f;
    }

    // ---- LDS overlay: rsum/csum reuse As (K-loop readers all done) ----
    float* rsum_lds = (float*)As;         // floats [0..127]
    float* csum_lds = rsum_lds + BM;      // floats [128..255]
    __syncthreads();                       // all waves past their LDS reads
    ((float*)As)[tid] = 0.0f;              // 256 floats = rsum + csum
    __syncthreads();

    // Row sums: sum over 16 cols (bc in-register, cq via shuffle).
    #pragma unroll
    for (int ar = 0; ar < 4; ++ar) {
        float rs[4];
        #pragma unroll
        for (int reg = 0; reg < 4; ++reg) {
            float v = acc[ar][0][reg] + acc[ar][1][reg] + acc[ar][2][reg] + acc[ar][3][reg];
            v += __shfl_xor(v, 1); v += __shfl_xor(v, 2);
            v += __shfl_xor(v, 4); v += __shfl_xor(v, 8);
            rs[reg] = v;
        }
        if (cq == 0) {
            #pragma unroll
            for (int reg = 0; reg < 4; ++reg)
                atomicAdd(&rsum_lds[wr * 64 + ar * 16 + quad * 4 + reg], rs[reg]);
        }
    }

    // Col sums (symmetry): only for off-diagonal blocks.
    if (!diagblk) {
        #pragma unroll
        for (int bc = 0; bc < 4; ++bc) {
            float cs = 0.0f;
            #pragma unroll
            for (int ar = 0; ar < 4; ++ar)
                #pragma unroll
                for (int reg = 0; reg < 4; ++reg)
                    cs += acc[ar][bc][reg];
            cs += __shfl_xor(cs, 16); cs += __shfl_xor(cs, 32);
            if (quad == 0) atomicAdd(&csum_lds[wc * 64 + bc * 16 + cq], cs);
        }
    }

    __syncthreads();
    if (tid < BM) atomicAdd(&rowsum[rowbase + tid], rsum_lds[tid]);
    else if (!diagblk) atomicAdd(&rowsum[colbase + tid - BM], csum_lds[tid - BM]);
#undef STAGE
#undef COMPUTE
}

// Kernel 3: single block. mean_r( log(rowsum[r]) - pos[r & (BHALF-1)] ).
__global__ __launch_bounds__(256) void finalize_kernel(
    const float* __restrict__ rowsum, const float* __restrict__ pos_ws,
    float* __restrict__ out)
{
    __shared__ float red[4];
    float s = 0.0f;
    for (int r = threadIdx.x; r < N_TOT; r += 256)
        s += __logf(rowsum[r]) - pos_ws[r & (BHALF - 1)];
    #pragma unroll
    for (int off = 1; off < 64; off <<= 1) s += __shfl_xor(s, off);
    int wave = threadIdx.x >> 6, lane = threadIdx.x & 63;
    if (lane == 0) red[wave] = s;
    __syncthreads();
    if (threadIdx.x == 0)
        out[0] = (red[0] + red[1] + red[2] + red[3]) * (1.0f / N_TOT);
}

extern "C" void kernel_launch(void* const* d_in, const int* in_sizes, int n_in,
                              void* d_out, int out_size, void* d_ws, size_t ws_size,
                              hipStream_t stream) {
    const float* zis = (const float*)d_in[0];
    const float* zjs = (const float*)d_in[1];
    float* rowsum = (float*)d_ws;                                   // 32 KB
    float* pos_ws = rowsum + N_TOT;                                 // 16 KB
    float* corr   = pos_ws + BHALF;                                 // 32 KB
    unsigned char* zq = (unsigned char*)(corr + N_TOT);             // 4 MB, 16B-aligned
    float* out = (float*)d_out;

    normalize_kernel<<<N_TOT / 4, 256, 0, stream>>>(zis, zjs, zq, corr, rowsum);
    ntxent_tri_kernel<<<NBLOCKS, 256, 0, stream>>>(zq, corr, rowsum, pos_ws);
    finalize_kernel<<<1, 256, 0, stream>>>(rowsum, pos_ws, out);
}

// Round 13
// 115.045 us; speedup vs baseline: 8.5542x; 1.0642x over previous
//
#include <hip/hip_runtime.h>

#define N_TOT 8192
#define BHALF 4096
#define D_DIM 512
#define BM 128
#define NTILE 64          // N_TOT / BM
#define NBLOCKS 2080      // NTILE*(NTILE+1)/2 upper-triangle tiles
#define BKQ 64            // K per chunk (fp8: 64 B rows)
#define NCHUNK 8          // D_DIM / BKQ
#define BUFS 4096         // shorts per buffer (128 rows x 64 B = 8 KB)
#define NBUF 3            // triple buffer: 2-deep prefetch (R11-proven)

// Q = e4m3(256 * z/||z||). corr[r] = ZSCALE/||Q_r|| (exact f32). Then
// acc*cr*cc = (2/ln2)*cos(Q_i,Q_j) exactly -> exp2() is exp(2*cos), and the
// pos LOGIT (2*cos) = corrected * ln2.
#define ZSCALE 1.69864368f      // sqrt(2/ln(2))
#define LN2F   0.69314718f
#define SCALE_Q 256.0f          // exact power of 2

typedef float f32x4 __attribute__((ext_vector_type(4)));
typedef long long i64;
typedef i64 i64x2 __attribute__((ext_vector_type(2)));   // 16B: one ds_read_b128

// ---- hand-rolled OCP e4m3fn converters ----
__device__ __forceinline__ unsigned int f2e4m3(float x) {
    union { float f; unsigned u; } v; v.f = x;
    unsigned a = v.u & 0x7fffffffu;
    unsigned s = (v.u >> 24) & 0x80u;
    unsigned m;
    if (a < 0x3C800000u) {                       // |x| < 2^-6 -> subnormal
        union { unsigned u; float f; } w; w.u = a;
        m = (unsigned)(w.f * 512.0f + 0.5f);
    } else {                                     // normal, RNE to 3 mantissa bits
        unsigned r = a + 0x7FFFFu + ((a >> 20) & 1u);
        unsigned e8 = (r >> 23) - 120u;
        m = (e8 << 3) | ((r >> 20) & 7u);
    }
    return s | m;
}
__device__ __forceinline__ float e4m32f(unsigned b) {
    unsigned e = (b >> 3) & 15u, m = b & 7u;
    float v;
    if (e) { union { unsigned u; float f; } w; w.u = ((e + 120u) << 23) | (m << 20); v = w.f; }
    else v = (float)m * 0x1p-9f;
    return (b & 0x80u) ? -v : v;
}

__device__ __forceinline__ float fast_exp2(float x) {
#if __has_builtin(__builtin_amdgcn_exp2f)
    return __builtin_amdgcn_exp2f(x);
#else
    return exp2f(x);
#endif
}

// Kernel 1: row L2-normalize [zjs; zis], quantize to e4m3 (x256), store
// per-row exact norm correction. Blocks 0..31 zero rowsum.
//
// K-INTERLEAVED PACKING (round 13): within each 64B chunk window, 8B unit
// g = 2*quad_slice + kk holds original k [64kc + 32kk + 8qs, +8). So a
// lane's TWO MFMA fragments (kk=0,1) are one contiguous 16B pair -> the tri
// kernel reads them with ONE ds_read_b128 (b64 reads had a measured 4.26M
// bank-conflict penalty in R12; the b128 pattern measured 0 in R6-R11).
// Lane l covers original k [8l,8l+8) -> uint2 slot (l&~7) + 2*(l&3) + ((l>>2)&1).
__global__ __launch_bounds__(256) void normalize_kernel(
    const float* __restrict__ zis, const float* __restrict__ zjs,
    unsigned char* __restrict__ zq, float* __restrict__ corr,
    float* __restrict__ rowsum)
{
    if (blockIdx.x < 32) rowsum[blockIdx.x * 256 + threadIdx.x] = 0.0f;
    int wave = threadIdx.x >> 6;
    int lane = threadIdx.x & 63;
    int row  = blockIdx.x * 4 + wave;
    const float* src = (row < BHALF) ? (zjs + (size_t)row * D_DIM)
                                     : (zis + (size_t)(row - BHALF) * D_DIM);
    const float4* src4 = (const float4*)src;
    float4 v0 = src4[lane * 2];
    float4 v1 = src4[lane * 2 + 1];
    float ss = v0.x*v0.x + v0.y*v0.y + v0.z*v0.z + v0.w*v0.w
             + v1.x*v1.x + v1.y*v1.y + v1.z*v1.z + v1.w*v1.w;
    #pragma unroll
    for (int off = 1; off < 64; off <<= 1) ss += __shfl_xor(ss, off);
    float scale = SCALE_Q / fmaxf(sqrtf(ss), 1e-8f);

    float vals[8] = {v0.x, v0.y, v0.z, v0.w, v1.x, v1.y, v1.z, v1.w};
    unsigned b[8]; float ssq = 0.0f;
    #pragma unroll
    for (int i = 0; i < 8; ++i) {
        b[i] = f2e4m3(vals[i] * scale);
        float d = e4m32f(b[i]);
        ssq += d * d;
    }
    #pragma unroll
    for (int off = 1; off < 64; off <<= 1) ssq += __shfl_xor(ssq, off);

    uint2 o;
    o.x = b[0] | (b[1] << 8) | (b[2] << 16) | (b[3] << 24);
    o.y = b[4] | (b[5] << 8) | (b[6] << 16) | (b[7] << 24);
    const int slot = (lane & ~7) + 2 * (lane & 3) + ((lane >> 2) & 1);
    ((uint2*)(zq + (size_t)row * D_DIM))[slot] = o;
    if (lane == 0) corr[row] = ZSCALE / fmaxf(sqrtf(ssq), 1e-8f);
}

// Kernel 2: upper-triangle 128x128 tiles of exp2(corr-scaled Q.Q^T).
//
// ROUND 13 — fp8 + b128 fragment reads via k-interleaved packing. One
// ds_read_b128 per operand per chunk yields BOTH kk fragments (i64x2.x/.y,
// register-aliased). Read instrs halve (16 b64 -> 8 b128/chunk) and the
// bank pattern matches R6's measured-0-conflict b128 scheme.
// Chassis: R11 triple-buffer counted-vmcnt + XCD swizzle (all verified).
//
// LDS pair-swizzle: stored 16B pair p holds global pair p ^ ((r>>1)&3);
// staging source c16 = (tid&3) ^ ((tid>>3)&3) (pair-level, packing-
// agnostic -> staging addresses unchanged from R12). Fragment read: global
// pair quad lives at stored pair quad ^ ((cq>>1)&3).
__global__ __launch_bounds__(256) void ntxent_tri_kernel(
    const unsigned char* __restrict__ zq, const float* __restrict__ corr,
    float* __restrict__ rowsum, float* __restrict__ pos_ws)
{
    __shared__ unsigned short As[NBUF * BUFS];   // 24 KB (3 buffers)
    __shared__ unsigned short Bs[NBUF * BUFS];   // 24 KB
    // rsum/csum overlay onto As after the K-loop -> total LDS 48 KB.

    const int tid  = threadIdx.x;
    const int wave = tid >> 6;
    const int lane = tid & 63;
    const int cq   = lane & 15;
    const int quad = lane >> 4;
    const int wr   = wave >> 1;    // wave row 0..1
    const int wc   = wave & 1;     // wave col 0..1

    // XCD-chunked bijective remap (2080 = 8 * 260).
    const int swzbid = (blockIdx.x & 7) * (NBLOCKS / 8) + (blockIdx.x >> 3);

    // swzbid -> (I,J), J-group-major (8 J-panels/group), I-major in group.
    int g = 0, rem = swzbid;
    while (rem >= 64 * g + 36) { rem -= 64 * g + 36; ++g; }
    int I, J;
    if (rem < 64 * g) { I = rem >> 3; J = 8 * g + (rem & 7); }
    else {
        rem -= 64 * g;
        int ii = 0;
        while (rem >= 8 - ii) { rem -= 8 - ii; ++ii; }
        I = 8 * g + ii;
        J = I + rem;
    }
    const int rowbase = I * BM;
    const int colbase = J * BM;
    const bool diagblk = (I == J);
    const bool posblk  = (J == I + NTILE / 2);   // contains (i, i+BHALF) pairs

    // Staging: thread t, round rnd covers row r = rnd*64 + (t>>2), 16B pair
    // p = t&3; stored pair p holds global pair p ^ ((r>>1)&3).
    const int c16 = (tid & 3) ^ ((tid >> 3) & 3);
    const unsigned char* pA0 = zq + (size_t)(rowbase + (tid >> 2)) * D_DIM + c16 * 16;
    const unsigned char* pA1 = pA0 + (size_t)64 * D_DIM;
    const unsigned char* pB0 = zq + (size_t)(colbase + (tid >> 2)) * D_DIM + c16 * 16;
    const unsigned char* pB1 = pB0 + (size_t)64 * D_DIM;
    const int dst0 = tid * 8;            // shorts; round 0
    const int dst1 = 2048 + tid * 8;     // shorts; round 1

    // Fragment reads (ds_read_b128): row ra = wr*64+t*16+cq; global pair
    // quad lives at stored pair quad ^ ((ra>>1)&3) = quad ^ ((cq>>1)&3).
    const int po = (quad ^ ((cq >> 1) & 3)) * 8;   // shorts
    int aOffS[4], bOffS[4];
    #pragma unroll
    for (int t = 0; t < 4; ++t) {
        aOffS[t] = (wr * 64 + t * 16 + cq) * 32 + po;
        bOffS[t] = (wc * 64 + t * 16 + cq) * 32 + po;
    }

    f32x4 acc[4][4];
    #pragma unroll
    for (int a = 0; a < 4; ++a)
        #pragma unroll
        for (int b = 0; b < 4; ++b)
            acc[a][b] = (f32x4){0.f, 0.f, 0.f, 0.f};

#define STAGE(buf) do {                                                          \
    const int dbase = (buf) * BUFS;                                              \
    __builtin_amdgcn_global_load_lds(                                            \
        (const __attribute__((address_space(1))) unsigned int*)pA0,              \
        (__attribute__((address_space(3))) unsigned int*)&As[dbase + dst0],      \
        16, 0, 0);                                                               \
    __builtin_amdgcn_global_load_lds(                                            \
        (const __attribute__((address_space(1))) unsigned int*)pA1,              \
        (__attribute__((address_space(3))) unsigned int*)&As[dbase + dst1],      \
        16, 0, 0);                                                               \
    __builtin_amdgcn_global_load_lds(                                            \
        (const __attribute__((address_space(1))) unsigned int*)pB0,              \
        (__attribute__((address_space(3))) unsigned int*)&Bs[dbase + dst0],      \
        16, 0, 0);                                                               \
    __builtin_amdgcn_global_load_lds(                                            \
        (const __attribute__((address_space(1))) unsigned int*)pB1,              \
        (__attribute__((address_space(3))) unsigned int*)&Bs[dbase + dst1],      \
        16, 0, 0);                                                               \
    pA0 += BKQ; pA1 += BKQ; pB0 += BKQ; pB1 += BKQ;                              \
} while (0)

#define COMPUTE(buf) do {                                                        \
    const int cbase = (buf) * BUFS;                                              \
    i64x2 af[4], bf[4];                                                          \
    _Pragma("unroll")                                                            \
    for (int t = 0; t < 4; ++t) {                                                \
        af[t] = *(const i64x2*)&As[cbase + aOffS[t]];                            \
        bf[t] = *(const i64x2*)&Bs[cbase + bOffS[t]];                            \
    }                                                                            \
    _Pragma("unroll")                                                            \
    for (int ar = 0; ar < 4; ++ar)                                               \
        _Pragma("unroll")                                                        \
        for (int bc = 0; bc < 4; ++bc)                                           \
            acc[ar][bc] = __builtin_amdgcn_mfma_f32_16x16x32_fp8_fp8(            \
                af[ar].x, bf[bc].x, acc[ar][bc], 0, 0, 0);                       \
    _Pragma("unroll")                                                            \
    for (int ar = 0; ar < 4; ++ar)                                               \
        _Pragma("unroll")                                                        \
        for (int bc = 0; bc < 4; ++bc)                                           \
            acc[ar][bc] = __builtin_amdgcn_mfma_f32_16x16x32_fp8_fp8(            \
                af[ar].y, bf[bc].y, acc[ar][bc], 0, 0, 0);                       \
} while (0)

    // Prologue: stage chunks 0,1 into buffers 0,1 (8 loads in flight).
    STAGE(0);
    STAGE(1);
    #pragma unroll
    for (int kc = 0; kc < NCHUNK; ++kc) {
        if (kc + 2 < NCHUNK) STAGE((kc + 2) % NBUF);      // 2-deep prefetch
        if (kc < NCHUNK - 2)
            asm volatile("s_waitcnt vmcnt(8)" ::: "memory");   // chunk kc landed
        else if (kc == NCHUNK - 2)
            asm volatile("s_waitcnt vmcnt(4)" ::: "memory");
        else
            asm volatile("s_waitcnt vmcnt(0)" ::: "memory");
        __builtin_amdgcn_s_barrier();                     // everyone's landed
        __builtin_amdgcn_sched_barrier(0);                // no hoisting across
        COMPUTE(kc % NBUF);
        __builtin_amdgcn_s_barrier();                     // readers done; buf free
    }

    // ---- exact norm correction: acc *= cr*cc -> (2/ln2)*cos(Q_i,Q_j) ----
    float cr[4][4], cc[4];
    #pragma unroll
    for (int ar = 0; ar < 4; ++ar)
        #pragma unroll
        for (int reg = 0; reg < 4; ++reg)
            cr[ar][reg] = corr[rowbase + wr * 64 + ar * 16 + quad * 4 + reg];
    #pragma unroll
    for (int bc = 0; bc < 4; ++bc)
        cc[bc] = corr[colbase + wc * 64 + bc * 16 + cq];
    #pragma unroll
    for (int ar = 0; ar < 4; ++ar)
        #pragma unroll
        for (int bc = 0; bc < 4; ++bc)
            #pragma unroll
            for (int reg = 0; reg < 4; ++reg)
                acc[ar][bc][reg] *= cr[ar][reg] * cc[bc];

    // pos extraction AFTER corr, BEFORE exp: logit (2*cos) = acc * ln2.
    if (posblk && wc == wr) {
        #pragma unroll
        for (int ar = 0; ar < 4; ++ar)
            #pragma unroll
            for (int reg = 0; reg < 4; ++reg)
                if (cq == quad * 4 + reg) {
                    int gr = rowbase + wr * 64 + ar * 16 + quad * 4 + reg;
                    pos_ws[gr] = acc[ar][ar][reg] * LN2F;
                }
    }

    // exp2 is the native op: one v_exp_f32 per element.
    #pragma unroll
    for (int ar = 0; ar < 4; ++ar)
        #pragma unroll
        for (int bc = 0; bc < 4; ++bc)
            #pragma unroll
            for (int reg = 0; reg < 4; ++reg)
                acc[ar][bc][reg] = fast_exp2(acc[ar][bc][reg]);
    if (diagblk && wr == wc) {
        #pragma unroll
        for (int ar = 0; ar < 4; ++ar)
            #pragma unroll
            for (int reg = 0; reg < 4; ++reg)
                if (cq == quad * 4 + reg) acc[ar][ar][reg] = 0.0f;
    }

    // ---- LDS overlay: rsum/csum reuse As (K-loop readers all done) ----
    float* rsum_lds = (float*)As;         // floats [0..127]
    float* csum_lds = rsum_lds + BM;      // floats [128..255]
    __syncthreads();                       // all waves past their LDS reads
    ((float*)As)[tid] = 0.0f;              // 256 floats = rsum + csum
    __syncthreads();

    // Row sums: sum over 16 cols (bc in-register, cq via shuffle).
    #pragma unroll
    for (int ar = 0; ar < 4; ++ar) {
        float rs[4];
        #pragma unroll
        for (int reg = 0; reg < 4; ++reg) {
            float v = acc[ar][0][reg] + acc[ar][1][reg] + acc[ar][2][reg] + acc[ar][3][reg];
            v += __shfl_xor(v, 1); v += __shfl_xor(v, 2);
            v += __shfl_xor(v, 4); v += __shfl_xor(v, 8);
            rs[reg] = v;
        }
        if (cq == 0) {
            #pragma unroll
            for (int reg = 0; reg < 4; ++reg)
                atomicAdd(&rsum_lds[wr * 64 + ar * 16 + quad * 4 + reg], rs[reg]);
        }
    }

    // Col sums (symmetry): only for off-diagonal blocks.
    if (!diagblk) {
        #pragma unroll
        for (int bc = 0; bc < 4; ++bc) {
            float cs = 0.0f;
            #pragma unroll
            for (int ar = 0; ar < 4; ++ar)
                #pragma unroll
                for (int reg = 0; reg < 4; ++reg)
                    cs += acc[ar][bc][reg];
            cs += __shfl_xor(cs, 16); cs += __shfl_xor(cs, 32);
            if (quad == 0) atomicAdd(&csum_lds[wc * 64 + bc * 16 + cq], cs);
        }
    }

    __syncthreads();
    if (tid < BM) atomicAdd(&rowsum[rowbase + tid], rsum_lds[tid]);
    else if (!diagblk) atomicAdd(&rowsum[colbase + tid - BM], csum_lds[tid - BM]);
#undef STAGE
#undef COMPUTE
}

// Kernel 3: single block. mean_r( log(rowsum[r]) - pos[r & (BHALF-1)] ).
__global__ __launch_bounds__(256) void finalize_kernel(
    const float* __restrict__ rowsum, const float* __restrict__ pos_ws,
    float* __restrict__ out)
{
    __shared__ float red[4];
    float s = 0.0f;
    for (int r = threadIdx.x; r < N_TOT; r += 256)
        s += __logf(rowsum[r]) - pos_ws[r & (BHALF - 1)];
    #pragma unroll
    for (int off = 1; off < 64; off <<= 1) s += __shfl_xor(s, off);
    int wave = threadIdx.x >> 6, lane = threadIdx.x & 63;
    if (lane == 0) red[wave] = s;
    __syncthreads();
    if (threadIdx.x == 0)
        out[0] = (red[0] + red[1] + red[2] + red[3]) * (1.0f / N_TOT);
}

extern "C" void kernel_launch(void* const* d_in, const int* in_sizes, int n_in,
                              void* d_out, int out_size, void* d_ws, size_t ws_size,
                              hipStream_t stream) {
    const float* zis = (const float*)d_in[0];
    const float* zjs = (const float*)d_in[1];
    float* rowsum = (float*)d_ws;                                   // 32 KB
    float* pos_ws = rowsum + N_TOT;                                 // 16 KB
    float* corr   = pos_ws + BHALF;                                 // 32 KB
    unsigned char* zq = (unsigned char*)(corr + N_TOT);             // 4 MB, 16B-aligned
    float* out = (float*)d_out;

    normalize_kernel<<<N_TOT / 4, 256, 0, stream>>>(zis, zjs, zq, corr, rowsum);
    ntxent_tri_kernel<<<NBLOCKS, 256, 0, stream>>>(zq, corr, rowsum, pos_ws);
    finalize_kernel<<<1, 256, 0, stream>>>(rowsum, pos_ws, out);
}

// Round 14
// 109.980 us; speedup vs baseline: 8.9481x; 1.0461x over previous
//
#include <hip/hip_runtime.h>

#define N_TOT 8192
#define BHALF 4096
#define D_DIM 512
#define BM 128
#define NTILE 64          // N_TOT / BM
#define NBLOCKS 2080      // NTILE*(NTILE+1)/2 upper-triangle tiles
#define BKQ 64            // K per chunk (fp8: 64 B rows)
#define NCHUNK 8          // D_DIM / BKQ
#define BUFS 4096         // shorts per buffer (128 rows x 64 B = 8 KB)
#define NBUF 3            // triple buffer: 2-deep prefetch (R11-proven)

// Q = e4m3(256 * z/||z||). corr[r] = ZSCALE/||Q_r|| (exact f32). Then
// acc*cr*cc = (2/ln2)*cos(Q_i,Q_j) exactly -> exp2() is exp(2*cos), and the
// pos LOGIT (2*cos) = corrected * ln2.
#define ZSCALE 1.69864368f      // sqrt(2/ln(2))
#define LN2F   0.69314718f
#define SCALE_Q 256.0f          // exact power of 2

typedef float f32x4 __attribute__((ext_vector_type(4)));
typedef long long i64;
typedef i64 i64x2 __attribute__((ext_vector_type(2)));   // 16B: one ds_read_b128

// ---- hand-rolled OCP e4m3fn converters ----
__device__ __forceinline__ unsigned int f2e4m3(float x) {
    union { float f; unsigned u; } v; v.f = x;
    unsigned a = v.u & 0x7fffffffu;
    unsigned s = (v.u >> 24) & 0x80u;
    unsigned m;
    if (a < 0x3C800000u) {                       // |x| < 2^-6 -> subnormal
        union { unsigned u; float f; } w; w.u = a;
        m = (unsigned)(w.f * 512.0f + 0.5f);
    } else {                                     // normal, RNE to 3 mantissa bits
        unsigned r = a + 0x7FFFFu + ((a >> 20) & 1u);
        unsigned e8 = (r >> 23) - 120u;
        m = (e8 << 3) | ((r >> 20) & 7u);
    }
    return s | m;
}
__device__ __forceinline__ float e4m32f(unsigned b) {
    unsigned e = (b >> 3) & 15u, m = b & 7u;
    float v;
    if (e) { union { unsigned u; float f; } w; w.u = ((e + 120u) << 23) | (m << 20); v = w.f; }
    else v = (float)m * 0x1p-9f;
    return (b & 0x80u) ? -v : v;
}

__device__ __forceinline__ float fast_exp2(float x) {
#if __has_builtin(__builtin_amdgcn_exp2f)
    return __builtin_amdgcn_exp2f(x);
#else
    return exp2f(x);
#endif
}

// Kernel 1: row L2-normalize [zjs; zis], quantize to e4m3 (x256), store
// per-row exact norm correction. Blocks 0..31 zero rowsum.
//
// K-INTERLEAVED PACKING (R13, verified -7.5us): within each 64B chunk
// window, 8B unit g = 2*quad_slice + kk holds original k
// [64kc + 32kk + 8qs, +8) -> a lane's TWO MFMA fragments are one contiguous
// 16B pair, read by ONE ds_read_b128 (b64 had 4.26M conflict cycles, R12).
// Lane l covers original k [8l,8l+8) -> uint2 slot (l&~7)+2(l&3)+((l>>2)&1).
__global__ __launch_bounds__(256) void normalize_kernel(
    const float* __restrict__ zis, const float* __restrict__ zjs,
    unsigned char* __restrict__ zq, float* __restrict__ corr,
    float* __restrict__ rowsum)
{
    if (blockIdx.x < 32) rowsum[blockIdx.x * 256 + threadIdx.x] = 0.0f;
    int wave = threadIdx.x >> 6;
    int lane = threadIdx.x & 63;
    int row  = blockIdx.x * 4 + wave;
    const float* src = (row < BHALF) ? (zjs + (size_t)row * D_DIM)
                                     : (zis + (size_t)(row - BHALF) * D_DIM);
    const float4* src4 = (const float4*)src;
    float4 v0 = src4[lane * 2];
    float4 v1 = src4[lane * 2 + 1];
    float ss = v0.x*v0.x + v0.y*v0.y + v0.z*v0.z + v0.w*v0.w
             + v1.x*v1.x + v1.y*v1.y + v1.z*v1.z + v1.w*v1.w;
    #pragma unroll
    for (int off = 1; off < 64; off <<= 1) ss += __shfl_xor(ss, off);
    float scale = SCALE_Q / fmaxf(sqrtf(ss), 1e-8f);

    float vals[8] = {v0.x, v0.y, v0.z, v0.w, v1.x, v1.y, v1.z, v1.w};
    unsigned b[8]; float ssq = 0.0f;
    #pragma unroll
    for (int i = 0; i < 8; ++i) {
        b[i] = f2e4m3(vals[i] * scale);
        float d = e4m32f(b[i]);
        ssq += d * d;
    }
    #pragma unroll
    for (int off = 1; off < 64; off <<= 1) ssq += __shfl_xor(ssq, off);

    uint2 o;
    o.x = b[0] | (b[1] << 8) | (b[2] << 16) | (b[3] << 24);
    o.y = b[4] | (b[5] << 8) | (b[6] << 16) | (b[7] << 24);
    const int slot = (lane & ~7) + 2 * (lane & 3) + ((lane >> 2) & 1);
    ((uint2*)(zq + (size_t)row * D_DIM))[slot] = o;
    if (lane == 0) corr[row] = ZSCALE / fmaxf(sqrtf(ssq), 1e-8f);
}

// Kernel 2: upper-triangle 128x128 tiles of exp2(corr-scaled Q.Q^T).
//
// ROUND 14 — SINGLE-BARRIER K-loop. Old: STAGE;vmcnt;barrier;COMPUTE;barrier
// (16 crossings). New per iter kc: {vmcnt(own chunk-kc loads); barrier;
// STAGE(kc+2); COMPUTE(kc)} -- the one barrier certifies BOTH (a) every
// wave's chunk-kc loads landed (each waited on its own before arriving) and
// (b) every wave finished COMPUTE(kc-1), so buffer (kc+2)%3 == (kc-1)%3's
// read-buffer is free to overwrite. Race screen: a fast wave reaches iter
// kc+1's STAGE of buffer (kc)%3 only after the kc+1 barrier, which a slow
// wave reaches only after its COMPUTE(kc) -- no read/write overlap.
// Steady-state wait = vmcnt(4) (uniform); tail vmcnt(4), vmcnt(0).
// Chassis: fp8 b128-packed fragments (R13), triple-buffer 2-deep prefetch
// (R11), XCD swizzle (R6). All verified; absmax 0 throughout.
__global__ __launch_bounds__(256) void ntxent_tri_kernel(
    const unsigned char* __restrict__ zq, const float* __restrict__ corr,
    float* __restrict__ rowsum, float* __restrict__ pos_ws)
{
    __shared__ unsigned short As[NBUF * BUFS];   // 24 KB (3 buffers)
    __shared__ unsigned short Bs[NBUF * BUFS];   // 24 KB
    // rsum/csum overlay onto As after the K-loop -> total LDS 48 KB.

    const int tid  = threadIdx.x;
    const int wave = tid >> 6;
    const int lane = tid & 63;
    const int cq   = lane & 15;
    const int quad = lane >> 4;
    const int wr   = wave >> 1;    // wave row 0..1
    const int wc   = wave & 1;     // wave col 0..1

    // XCD-chunked bijective remap (2080 = 8 * 260).
    const int swzbid = (blockIdx.x & 7) * (NBLOCKS / 8) + (blockIdx.x >> 3);

    // swzbid -> (I,J), J-group-major (8 J-panels/group), I-major in group.
    int g = 0, rem = swzbid;
    while (rem >= 64 * g + 36) { rem -= 64 * g + 36; ++g; }
    int I, J;
    if (rem < 64 * g) { I = rem >> 3; J = 8 * g + (rem & 7); }
    else {
        rem -= 64 * g;
        int ii = 0;
        while (rem >= 8 - ii) { rem -= 8 - ii; ++ii; }
        I = 8 * g + ii;
        J = I + rem;
    }
    const int rowbase = I * BM;
    const int colbase = J * BM;
    const bool diagblk = (I == J);
    const bool posblk  = (J == I + NTILE / 2);   // contains (i, i+BHALF) pairs

    // Staging: thread t, round rnd covers row r = rnd*64 + (t>>2), 16B pair
    // p = t&3; stored pair p holds global pair p ^ ((r>>1)&3).
    const int c16 = (tid & 3) ^ ((tid >> 3) & 3);
    const unsigned char* pA0 = zq + (size_t)(rowbase + (tid >> 2)) * D_DIM + c16 * 16;
    const unsigned char* pA1 = pA0 + (size_t)64 * D_DIM;
    const unsigned char* pB0 = zq + (size_t)(colbase + (tid >> 2)) * D_DIM + c16 * 16;
    const unsigned char* pB1 = pB0 + (size_t)64 * D_DIM;
    const int dst0 = tid * 8;            // shorts; round 0
    const int dst1 = 2048 + tid * 8;     // shorts; round 1

    // Fragment reads (ds_read_b128): row ra = wr*64+t*16+cq; global pair
    // quad lives at stored pair quad ^ ((ra>>1)&3) = quad ^ ((cq>>1)&3).
    const int po = (quad ^ ((cq >> 1) & 3)) * 8;   // shorts
    int aOffS[4], bOffS[4];
    #pragma unroll
    for (int t = 0; t < 4; ++t) {
        aOffS[t] = (wr * 64 + t * 16 + cq) * 32 + po;
        bOffS[t] = (wc * 64 + t * 16 + cq) * 32 + po;
    }

    f32x4 acc[4][4];
    #pragma unroll
    for (int a = 0; a < 4; ++a)
        #pragma unroll
        for (int b = 0; b < 4; ++b)
            acc[a][b] = (f32x4){0.f, 0.f, 0.f, 0.f};

#define STAGE(buf) do {                                                          \
    const int dbase = (buf) * BUFS;                                              \
    __builtin_amdgcn_global_load_lds(                                            \
        (const __attribute__((address_space(1))) unsigned int*)pA0,              \
        (__attribute__((address_space(3))) unsigned int*)&As[dbase + dst0],      \
        16, 0, 0);                                                               \
    __builtin_amdgcn_global_load_lds(                                            \
        (const __attribute__((address_space(1))) unsigned int*)pA1,              \
        (__attribute__((address_space(3))) unsigned int*)&As[dbase + dst1],      \
        16, 0, 0);                                                               \
    __builtin_amdgcn_global_load_lds(                                            \
        (const __attribute__((address_space(1))) unsigned int*)pB0,              \
        (__attribute__((address_space(3))) unsigned int*)&Bs[dbase + dst0],      \
        16, 0, 0);                                                               \
    __builtin_amdgcn_global_load_lds(                                            \
        (const __attribute__((address_space(1))) unsigned int*)pB1,              \
        (__attribute__((address_space(3))) unsigned int*)&Bs[dbase + dst1],      \
        16, 0, 0);                                                               \
    pA0 += BKQ; pA1 += BKQ; pB0 += BKQ; pB1 += BKQ;                              \
} while (0)

#define COMPUTE(buf) do {                                                        \
    const int cbase = (buf) * BUFS;                                              \
    i64x2 af[4], bf[4];                                                          \
    _Pragma("unroll")                                                            \
    for (int t = 0; t < 4; ++t) {                                                \
        af[t] = *(const i64x2*)&As[cbase + aOffS[t]];                            \
        bf[t] = *(const i64x2*)&Bs[cbase + bOffS[t]];                            \
    }                                                                            \
    _Pragma("unroll")                                                            \
    for (int ar = 0; ar < 4; ++ar)                                               \
        _Pragma("unroll")                                                        \
        for (int bc = 0; bc < 4; ++bc)                                           \
            acc[ar][bc] = __builtin_amdgcn_mfma_f32_16x16x32_fp8_fp8(            \
                af[ar].x, bf[bc].x, acc[ar][bc], 0, 0, 0);                       \
    _Pragma("unroll")                                                            \
    for (int ar = 0; ar < 4; ++ar)                                               \
        _Pragma("unroll")                                                        \
        for (int bc = 0; bc < 4; ++bc)                                           \
            acc[ar][bc] = __builtin_amdgcn_mfma_f32_16x16x32_fp8_fp8(            \
                af[ar].y, bf[bc].y, acc[ar][bc], 0, 0, 0);                       \
} while (0)

    // Prologue: stage chunks 0,1 into buffers 0,1 (8 loads in flight).
    STAGE(0);
    STAGE(1);
    #pragma unroll
    for (int kc = 0; kc < NCHUNK; ++kc) {
        if (kc < NCHUNK - 1)
            asm volatile("s_waitcnt vmcnt(4)" ::: "memory");   // my chunk-kc loads landed
        else
            asm volatile("s_waitcnt vmcnt(0)" ::: "memory");
        __builtin_amdgcn_s_barrier();        // all landed + all done COMPUTE(kc-1)
        __builtin_amdgcn_sched_barrier(0);   // no hoisting across
        if (kc + 2 < NCHUNK) STAGE((kc + 2) % NBUF);  // overwrite kc-1's read buf
        COMPUTE(kc % NBUF);
    }

    // ---- exact norm correction: acc *= cr*cc -> (2/ln2)*cos(Q_i,Q_j) ----
    float cr[4][4], cc[4];
    #pragma unroll
    for (int ar = 0; ar < 4; ++ar)
        #pragma unroll
        for (int reg = 0; reg < 4; ++reg)
            cr[ar][reg] = corr[rowbase + wr * 64 + ar * 16 + quad * 4 + reg];
    #pragma unroll
    for (int bc = 0; bc < 4; ++bc)
        cc[bc] = corr[colbase + wc * 64 + bc * 16 + cq];
    #pragma unroll
    for (int ar = 0; ar < 4; ++ar)
        #pragma unroll
        for (int bc = 0; bc < 4; ++bc)
            #pragma unroll
            for (int reg = 0; reg < 4; ++reg)
                acc[ar][bc][reg] *= cr[ar][reg] * cc[bc];

    // pos extraction AFTER corr, BEFORE exp: logit (2*cos) = acc * ln2.
    if (posblk && wc == wr) {
        #pragma unroll
        for (int ar = 0; ar < 4; ++ar)
            #pragma unroll
            for (int reg = 0; reg < 4; ++reg)
                if (cq == quad * 4 + reg) {
                    int gr = rowbase + wr * 64 + ar * 16 + quad * 4 + reg;
                    pos_ws[gr] = acc[ar][ar][reg] * LN2F;
                }
    }

    // exp2 is the native op: one v_exp_f32 per element.
    #pragma unroll
    for (int ar = 0; ar < 4; ++ar)
        #pragma unroll
        for (int bc = 0; bc < 4; ++bc)
            #pragma unroll
            for (int reg = 0; reg < 4; ++reg)
                acc[ar][bc][reg] = fast_exp2(acc[ar][bc][reg]);
    if (diagblk && wr == wc) {
        #pragma unroll
        for (int ar = 0; ar < 4; ++ar)
            #pragma unroll
            for (int reg = 0; reg < 4; ++reg)
                if (cq == quad * 4 + reg) acc[ar][ar][reg] = 0.0f;
    }

    // ---- LDS overlay: rsum/csum reuse As (K-loop readers all done) ----
    float* rsum_lds = (float*)As;         // floats [0..127]
    float* csum_lds = rsum_lds + BM;      // floats [128..255]
    __syncthreads();                       // all waves past their LDS reads
    ((float*)As)[tid] = 0.0f;              // 256 floats = rsum + csum
    __syncthreads();

    // Row sums: sum over 16 cols (bc in-register, cq via shuffle).
    #pragma unroll
    for (int ar = 0; ar < 4; ++ar) {
        float rs[4];
        #pragma unroll
        for (int reg = 0; reg < 4; ++reg) {
            float v = acc[ar][0][reg] + acc[ar][1][reg] + acc[ar][2][reg] + acc[ar][3][reg];
            v += __shfl_xor(v, 1); v += __shfl_xor(v, 2);
            v += __shfl_xor(v, 4); v += __shfl_xor(v, 8);
            rs[reg] = v;
        }
        if (cq == 0) {
            #pragma unroll
            for (int reg = 0; reg < 4; ++reg)
                atomicAdd(&rsum_lds[wr * 64 + ar * 16 + quad * 4 + reg], rs[reg]);
        }
    }

    // Col sums (symmetry): only for off-diagonal blocks.
    if (!diagblk) {
        #pragma unroll
        for (int bc = 0; bc < 4; ++bc) {
            float cs = 0.0f;
            #pragma unroll
            for (int ar = 0; ar < 4; ++ar)
                #pragma unroll
                for (int reg = 0; reg < 4; ++reg)
                    cs += acc[ar][bc][reg];
            cs += __shfl_xor(cs, 16); cs += __shfl_xor(cs, 32);
            if (quad == 0) atomicAdd(&csum_lds[wc * 64 + bc * 16 + cq], cs);
        }
    }

    __syncthreads();
    if (tid < BM) atomicAdd(&rowsum[rowbase + tid], rsum_lds[tid]);
    else if (!diagblk) atomicAdd(&rowsum[colbase + tid - BM], csum_lds[tid - BM]);
#undef STAGE
#undef COMPUTE
}

// Kernel 3: single block, 1024 threads (16 waves: 4x the load-level
// parallelism of the old 256-thread version -- this kernel is pure
// L2-latency-bound). mean_r( log(rowsum[r]) - pos[r & (BHALF-1)] ).
__global__ __launch_bounds__(1024) void finalize_kernel(
    const float* __restrict__ rowsum, const float* __restrict__ pos_ws,
    float* __restrict__ out)
{
    __shared__ float red[16];
    float s = 0.0f;
    for (int r = threadIdx.x; r < N_TOT; r += 1024)
        s += __logf(rowsum[r]) - pos_ws[r & (BHALF - 1)];
    #pragma unroll
    for (int off = 1; off < 64; off <<= 1) s += __shfl_xor(s, off);
    int wave = threadIdx.x >> 6, lane = threadIdx.x & 63;
    if (lane == 0) red[wave] = s;
    __syncthreads();
    if (threadIdx.x < 64) {
        float v = (threadIdx.x < 16) ? red[threadIdx.x] : 0.0f;
        #pragma unroll
        for (int off = 1; off < 16; off <<= 1) v += __shfl_xor(v, off);
        if (threadIdx.x == 0) out[0] = v * (1.0f / N_TOT);
    }
}

extern "C" void kernel_launch(void* const* d_in, const int* in_sizes, int n_in,
                              void* d_out, int out_size, void* d_ws, size_t ws_size,
                              hipStream_t stream) {
    const float* zis = (const float*)d_in[0];
    const float* zjs = (const float*)d_in[1];
    float* rowsum = (float*)d_ws;                                   // 32 KB
    float* pos_ws = rowsum + N_TOT;                                 // 16 KB
    float* corr   = pos_ws + BHALF;                                 // 32 KB
    unsigned char* zq = (unsigned char*)(corr + N_TOT);             // 4 MB, 16B-aligned
    float* out = (float*)d_out;

    normalize_kernel<<<N_TOT / 4, 256, 0, stream>>>(zis, zjs, zq, corr, rowsum);
    ntxent_tri_kernel<<<NBLOCKS, 256, 0, stream>>>(zq, corr, rowsum, pos_ws);
    finalize_kernel<<<1, 1024, 0, stream>>>(rowsum, pos_ws, out);
}